// Round 5
// baseline (8862.621 us; speedup 1.0000x reference)
//
#include <hip/hip_runtime.h>
#include <stdint.h>

#define NVV 300000
#define NFF 1500000
#define NE  9000000
#define NGRID 1225
#define NB   262144        // key-space buckets = 2^18
#define BSH  14            // bucket = skey >> BSH

// d_out layout (float32 element offsets)
#define OFF_VERTS 0
#define OFF_FACES 27000000
#define OFF_MASK  36000000
#define OFF_NTRI  39000000
#define OFF_CROSS 40500000
#define OFF_UVS   49500000
#define OFF_UVIDX 61505000

// ALL scratch lives in d_out's tail (uvs + uv_idx regions, 21M els), which is
// overwritten with final uvs/uv_idx values LAST. d_ws never used.
#define S_EB    49500000u          // bEb: 9,000,000 u32 (skeys), in uvs region
#define S_REP_E 61505000u          // bRep: 9,000,000 bytes = 2,250,000 els
#define S_CNT1  63755000u          // 262,144
#define S_CNT2  64017144u          // 262,144
#define S_DCNT  64279288u          // 262,144
#define S_FLAGS 64541432u          // 8  [0]=hasInvalid [1]=validZeroKey
#define S_OFF1  64541440u          // 262,145
#define S_BASE2 64803585u          // 262,145
#define S_BSUMS 65065730u          // 1024
#define S_SSUMS 65066754u          // 1024  (ends 65,067,778 < 70,505,000)

// tri table packed: entry e (local edge id 0..5, or 7 for -1) in bits [3e,3e+3)
#define ENC3(x) ((unsigned)(((x) < 0) ? 7 : (x)))
#define PACK6(a,b,c,d,e,f) (ENC3(a) | (ENC3(b)<<3) | (ENC3(c)<<6) | \
                            (ENC3(d)<<9) | (ENC3(e)<<12) | (ENC3(f)<<15))
__constant__ unsigned TROW[16] = {
    PACK6(-1,-1,-1,-1,-1,-1), PACK6(1,0,2,-1,-1,-1), PACK6(4,0,3,-1,-1,-1), PACK6(1,4,2,1,3,4),
    PACK6(3,1,5,-1,-1,-1),    PACK6(2,3,0,2,5,3),    PACK6(1,4,0,1,5,4),    PACK6(4,2,5,-1,-1,-1),
    PACK6(4,5,2,-1,-1,-1),    PACK6(4,1,0,4,5,1),    PACK6(3,2,0,3,5,2),    PACK6(1,3,5,-1,-1,-1),
    PACK6(4,1,2,4,3,1),       PACK6(3,0,4,-1,-1,-1), PACK6(2,0,1,-1,-1,-1), PACK6(-1,-1,-1,-1,-1,-1)};

__device__ __forceinline__ int tidx(const float* sdf, int v0, int v1, int v2, int v3) {
    int ti = 0;
    if (sdf[v0] > 0.0f) ti |= 1;
    if (sdf[v1] > 0.0f) ti |= 2;
    if (sdf[v2] > 0.0f) ti |= 4;
    if (sdf[v3] > 0.0f) ti |= 8;
    return ti;
}

// wrapped int32 key (x64-disabled JAX semantics), shifted to unsigned order
__device__ __forceinline__ unsigned skey_of(int a, int b) {
    int ea = a < b ? a : b;
    int eb = a < b ? b : a;
    unsigned ukey = (unsigned)ea * 300000u + (unsigned)eb;   // wraps like int32
    return ukey ^ 0x80000000u;                               // unsigned cmp == signed cmp
}

// K0: ntri + mask outputs, bucket counts, flags
__global__ void k0_count(const int* __restrict__ tets, const float* __restrict__ sdf,
                         unsigned* __restrict__ cnt1, unsigned* __restrict__ flags,
                         float* __restrict__ out_ntri, float* __restrict__ out_mask) {
    int f = blockIdx.x * 256 + threadIdx.x;
    if (f >= NFF) return;
    const int4 tv = ((const int4*)tets)[f];
    int v0 = tv.x, v1 = tv.y, v2 = tv.z, v3 = tv.w;
    int ti = tidx(sdf, v0, v1, v2, v3);
    unsigned row = TROW[ti];
    bool has1 = (row & 7u) != 7u;
    bool has2 = ((row >> 9) & 7u) != 7u;
    int nt = has2 ? 2 : (has1 ? 1 : 0);
    out_ntri[f] = (float)nt;
    out_mask[f * 2 + 0] = has1 ? 1.0f : 0.0f;
    out_mask[f * 2 + 1] = has2 ? 1.0f : 0.0f;
    if (!has1) { atomicOr(&flags[0], 1u); return; }   // ti==0 or 15 -> invalid tet
#define CNT_EDGE(A,B) { unsigned sk_ = skey_of(A, B); \
    if (sk_ == 0x80000000u) atomicOr(&flags[1], 1u); \
    atomicAdd(&cnt1[sk_ >> BSH], 1u); }
    CNT_EDGE(v0, v1) CNT_EDGE(v0, v2) CNT_EDGE(v0, v3)
    CNT_EDGE(v1, v2) CNT_EDGE(v1, v3) CNT_EDGE(v2, v3)
#undef CNT_EDGE
}

// exclusive block scan (Hillis-Steele); bsums optional
__global__ void scan_block(const unsigned* __restrict__ in, unsigned* __restrict__ out,
                           unsigned* __restrict__ bsums, int n) {
    __shared__ unsigned s[1024];
    int tid = threadIdx.x;
    int g = blockIdx.x * 1024 + tid;
    unsigned v = (g < n) ? in[g] : 0u;
    s[tid] = v;
    __syncthreads();
    for (int off = 1; off < 1024; off <<= 1) {
        unsigned t = (tid >= off) ? s[tid - off] : 0u;
        __syncthreads();
        s[tid] += t;
        __syncthreads();
    }
    if (g < n) out[g] = s[tid] - v;  // exclusive
    if (tid == 1023 && bsums) bsums[blockIdx.x] = s[1023];
}

__global__ void scan_add(unsigned* __restrict__ out, const unsigned* __restrict__ ssums,
                         const unsigned* __restrict__ in, unsigned* __restrict__ total, int n) {
    int g = blockIdx.x * 1024 + threadIdx.x;
    if (g >= n) return;
    unsigned v = out[g] + ssums[g >> 10];
    out[g] = v;
    if (g == n - 1) *total = v + in[g];
}

// K1: scatter skeys into buckets
__global__ void k1_scatter(const int* __restrict__ tets, const float* __restrict__ sdf,
                           const unsigned* __restrict__ off1, unsigned* __restrict__ cnt2,
                           unsigned* __restrict__ bEb) {
    int f = blockIdx.x * 256 + threadIdx.x;
    if (f >= NFF) return;
    const int4 tv = ((const int4*)tets)[f];
    int v0 = tv.x, v1 = tv.y, v2 = tv.z, v3 = tv.w;
    int ti = tidx(sdf, v0, v1, v2, v3);
    if (ti == 0 || ti == 15) return;
#define SCAT_EDGE(A,B) { unsigned sk_ = skey_of(A, B); unsigned b_ = sk_ >> BSH; \
    unsigned p_ = off1[b_] + atomicAdd(&cnt2[b_], 1u); \
    bEb[p_] = sk_; }
    SCAT_EDGE(v0, v1) SCAT_EDGE(v0, v2) SCAT_EDGE(v0, v3)
    SCAT_EDGE(v1, v2) SCAT_EDGE(v1, v3) SCAT_EDGE(v2, v3)
#undef SCAT_EDGE
}

// K2: representative = first position in bucket holding its skey
__global__ void k2_rep(const unsigned* __restrict__ off1, const unsigned* __restrict__ bEb,
                       unsigned char* __restrict__ bRep, unsigned* __restrict__ dcnt) {
    unsigned p = blockIdx.x * 256 + threadIdx.x;
    unsigned total = off1[NB];
    if (p >= total) return;
    unsigned mySk = bEb[p];
    unsigned b = mySk >> BSH;
    unsigned s = off1[b];
    bool rep = true;
    for (unsigned q = s; q < p; q++) {
        if (bEb[q] == mySk) { rep = false; break; }
    }
    bRep[p] = rep ? 1 : 0;
    if (rep) atomicAdd(&dcnt[b], 1u);
}

// decode wrapped int32 key -> gather indices (JAX floor-div + negative wrap)
__device__ __forceinline__ void decode_key(unsigned sk, int* iua, int* iub) {
    int key = (int)(sk ^ 0x80000000u);
    long long kk = (long long)key;
    long long q = kk / 300000LL;
    long long r = kk - q * 300000LL;
    if (r < 0) { q -= 1; r += 300000LL; }
    int ua = (int)q;
    if (ua < 0) ua += NVV;       // JAX negative-index wrap
    *iua = ua;
    *iub = (int)r;
}

// K3: representatives compute distinct rank, write verts + cross
__global__ void k3_verts(const float* __restrict__ pos, const float* __restrict__ sdf,
                         const unsigned* __restrict__ off1, const unsigned* __restrict__ bEb,
                         const unsigned char* __restrict__ bRep,
                         const unsigned* __restrict__ base2, const unsigned* __restrict__ flags,
                         float* __restrict__ out_verts, float* __restrict__ out_cross) {
    unsigned p = blockIdx.x * 256 + threadIdx.x;
    unsigned total = off1[NB];
    if (p >= total) return;
    if (!bRep[p]) return;
    unsigned mySk = bEb[p];
    unsigned b = mySk >> BSH;
    unsigned s = off1[b], e = off1[b + 1];
    unsigned rank = 0;
    for (unsigned q = s; q < e; q++) {
        if (bRep[q] && bEb[q] < mySk) rank++;
    }
    bool needZ = (flags[0] && !flags[1]);
    unsigned g = base2[b] + rank + ((needZ && mySk > 0x80000000u) ? 1u : 0u);
    int ua, ub;
    decode_key(mySk, &ua, &ub);
    float s0 = sdf[ua], s1 = sdf[ub];
    bool cr = (s0 > 0.0f) != (s1 > 0.0f);
    out_cross[g] = cr ? 1.0f : 0.0f;
    if (cr) {
        float denom = s0 - s1;
        float wa = -s1 / denom, wb = s0 / denom;
        out_verts[g * 3 + 0] = wa * pos[ua * 3 + 0] + wb * pos[ub * 3 + 0];
        out_verts[g * 3 + 1] = wa * pos[ua * 3 + 1] + wb * pos[ub * 3 + 1];
        out_verts[g * 3 + 2] = wa * pos[ua * 3 + 2] + wb * pos[ub * 3 + 2];
    }
}

// per-edge global unique index (same formula as k3)
__device__ __forceinline__ float edge_g(int a, int b, const unsigned* __restrict__ off1,
                                        const unsigned* __restrict__ bEb,
                                        const unsigned char* __restrict__ bRep,
                                        const unsigned* __restrict__ base2, bool needZ) {
    unsigned sk = skey_of(a, b);
    unsigned bk = sk >> BSH;
    unsigned s = off1[bk], en = off1[bk + 1];
    unsigned rank = 0;
    for (unsigned q = s; q < en; q++) {
        rank += (bRep[q] && bEb[q] < sk) ? 1u : 0u;
    }
    return (float)(base2[bk] + rank + ((needZ && sk > 0x80000000u) ? 1u : 0u));
}

// K5: faces
__global__ void k5_faces(const int* __restrict__ tets, const float* __restrict__ sdf,
                         const unsigned* __restrict__ off1, const unsigned* __restrict__ bEb,
                         const unsigned char* __restrict__ bRep,
                         const unsigned* __restrict__ base2, const unsigned* __restrict__ flags,
                         float* __restrict__ out_faces) {
    int f = blockIdx.x * 256 + threadIdx.x;
    if (f >= NFF) return;
    const int4 tv = ((const int4*)tets)[f];
    int v0 = tv.x, v1 = tv.y, v2 = tv.z, v3 = tv.w;
    int ti = tidx(sdf, v0, v1, v2, v3);
    unsigned row = TROW[ti];
    bool has1 = (row & 7u) != 7u;
    bool has2 = ((row >> 9) & 7u) != 7u;
    float* of = out_faces + (size_t)f * 6;
    if (!has1) {
        of[0] = -1.0f; of[1] = -1.0f; of[2] = -1.0f;
        of[3] = -1.0f; of[4] = -1.0f; of[5] = -1.0f;
        return;
    }
    bool needZ = (flags[0] && !flags[1]);
    float g0 = edge_g(v0, v1, off1, bEb, bRep, base2, needZ);
    float g1 = edge_g(v0, v2, off1, bEb, bRep, base2, needZ);
    float g2 = edge_g(v0, v3, off1, bEb, bRep, base2, needZ);
    float g3 = edge_g(v1, v2, off1, bEb, bRep, base2, needZ);
    float g4 = edge_g(v1, v3, off1, bEb, bRep, base2, needZ);
    float g5 = edge_g(v2, v3, off1, bEb, bRep, base2, needZ);
    unsigned l0 = row & 7u,         l1 = (row >> 3) & 7u,  l2 = (row >> 6) & 7u;
    unsigned l3 = (row >> 9) & 7u,  l4 = (row >> 12) & 7u, l5 = (row >> 15) & 7u;
#define SEL(L) ((L) == 0u ? g0 : (L) == 1u ? g1 : (L) == 2u ? g2 : \
                (L) == 3u ? g3 : (L) == 4u ? g4 : g5)
    of[0] = SEL(l0);
    of[1] = SEL(l1);
    of[2] = SEL(l2);
    of[3] = has2 ? SEL(l3) : -1.0f;
    of[4] = has2 ? SEL(l4) : -1.0f;
    of[5] = has2 ? SEL(l5) : -1.0f;
#undef SEL
}

// K6: uv atlas — runs LAST over the uvs region (was bEb scratch)
__global__ void k6_uvs(float* __restrict__ out_uvs) {
    int c = blockIdx.x * 256 + threadIdx.x;
    if (c >= NGRID * NGRID) return;
    int i = c / NGRID, j = c - i * NGRID;
    const float inv = 1.0f / (float)NGRID;
    const float pad = 0.9f / (float)NGRID;
    float x = (float)j * inv;
    float y = (float)i * inv;
    float* o = out_uvs + (size_t)c * 8;
    o[0] = x;       o[1] = y;
    o[2] = x + pad; o[3] = y;
    o[4] = x + pad; o[5] = y + pad;
    o[6] = x;       o[7] = y + pad;
}

// K7: uv_idx — runs LAST over the uv_idx region (was bRep/counters scratch)
__global__ void k7_uvidx(float* __restrict__ out_uvidx) {
    int f = blockIdx.x * 256 + threadIdx.x;
    if (f >= NFF) return;
    float base = (float)(4 * f);
    float* uvi = out_uvidx + (size_t)f * 6;
    uvi[0] = base; uvi[1] = base + 1.0f; uvi[2] = base + 2.0f;
    uvi[3] = base; uvi[4] = base + 2.0f; uvi[5] = base + 3.0f;
}

extern "C" void kernel_launch(void* const* d_in, const int* in_sizes, int n_in,
                              void* d_out, int out_size, void* d_ws, size_t ws_size,
                              hipStream_t stream) {
    const float* pos = (const float*)d_in[0];
    const float* sdf = (const float*)d_in[1];
    const int* tets = (const int*)d_in[2];
    float* out = (float*)d_out;
    unsigned* u = (unsigned*)d_out;

    unsigned* bEb   = u + S_EB;
    unsigned char* bRep = (unsigned char*)d_out + (size_t)S_REP_E * 4;
    unsigned* cnt1  = u + S_CNT1;
    unsigned* cnt2  = u + S_CNT2;
    unsigned* dcnt  = u + S_DCNT;
    unsigned* flags = u + S_FLAGS;
    unsigned* off1  = u + S_OFF1;
    unsigned* base2 = u + S_BASE2;
    unsigned* bsums = u + S_BSUMS;
    unsigned* ssums = u + S_SSUMS;

    // zero counters+flags (contiguous: cnt1,cnt2,dcnt,flags), verts, cross
    hipMemsetAsync(cnt1, 0, (size_t)(3 * NB + 8) * 4, stream);
    hipMemsetAsync(out + OFF_VERTS, 0, (size_t)27000000 * 4, stream);
    hipMemsetAsync(out + OFF_CROSS, 0, (size_t)9000000 * 4, stream);

    dim3 blk(256);
    int gF = (NFF + 255) / 256;
    int gE = (NE + 255) / 256;

    k0_count<<<gF, blk, 0, stream>>>(tets, sdf, cnt1, flags,
                                     out + OFF_NTRI, out + OFF_MASK);

    // scan1: cnt1 -> off1 (+ total at off1[NB])
    const int n = NB, nb = NB / 1024;  // 256 blocks
    scan_block<<<nb, 1024, 0, stream>>>(cnt1, off1, bsums, n);
    scan_block<<<1, 1024, 0, stream>>>(bsums, ssums, nullptr, nb);
    scan_add<<<nb, 1024, 0, stream>>>(off1, ssums, cnt1, off1 + NB, n);

    k1_scatter<<<gF, blk, 0, stream>>>(tets, sdf, off1, cnt2, bEb);
    k2_rep<<<gE, blk, 0, stream>>>(off1, bEb, bRep, dcnt);

    // scan2: dcnt -> base2
    scan_block<<<nb, 1024, 0, stream>>>(dcnt, base2, bsums, n);
    scan_block<<<1, 1024, 0, stream>>>(bsums, ssums, nullptr, nb);
    scan_add<<<nb, 1024, 0, stream>>>(base2, ssums, dcnt, base2 + NB, n);

    k3_verts<<<gE, blk, 0, stream>>>(pos, sdf, off1, bEb, bRep, base2, flags,
                                     out + OFF_VERTS, out + OFF_CROSS);
    k5_faces<<<gF, blk, 0, stream>>>(tets, sdf, off1, bEb, bRep, base2, flags,
                                     out + OFF_FACES);

    // scratch regions are free now — write the real uvs / uv_idx outputs
    int gC = (NGRID * NGRID + 255) / 256;
    k6_uvs<<<gC, blk, 0, stream>>>(out + OFF_UVS);
    k7_uvidx<<<gF, blk, 0, stream>>>(out + OFF_UVIDX);
}

// Round 6
// 1746.939 us; speedup vs baseline: 5.0732x; 5.0732x over previous
//
#include <hip/hip_runtime.h>
#include <stdint.h>

#define NVV 300000
#define NFF 1500000
#define NE  9000000
#define NGRID 1225
#define NB   262144        // key-space buckets = 2^18
#define BSH  14            // bucket = skey >> BSH

// d_out layout (float32 element offsets)
#define OFF_VERTS 0
#define OFF_FACES 27000000
#define OFF_MASK  36000000
#define OFF_NTRI  39000000
#define OFF_CROSS 40500000
#define OFF_UVS   49500000
#define OFF_UVIDX 61505000

// ALL scratch lives in d_out (uvs + uv_idx + faces regions), overwritten with
// final values LAST. d_ws never used.
#define S_EB    49500000u            // bEb: 9,000,000 u32 skeys (uvs region)
#define S_CNT1  58500000u            // NB
#define S_CNT2  (S_CNT1 + NB)        // NB
#define S_DCNT  (S_CNT2 + NB)        // NB
#define S_FLAGS (S_DCNT + NB)        // 8  [0]=hasInvalid [1]=validZeroKey
#define S_OFF1  (S_FLAGS + 8)        // NB+1
#define S_BASE2 (S_OFF1 + NB + 1)    // NB+1
#define S_BSUMS (S_BASE2 + NB + 1)   // 1024
#define S_SSUMS (S_BSUMS + 1024)     // 1024 (ends 59,812,778 < 61,505,000)
#define S_ORIG  61505000u            // bOrig: 9,000,000 u32 (uv_idx region); bit31 = rep flag
// idx_map: 9,000,000 u32 stored in the faces region (read+overwritten by k5)

// tri table packed: entry e (local edge id 0..5, or 7 for -1) in bits [3e,3e+3)
#define ENC3(x) ((unsigned)(((x) < 0) ? 7 : (x)))
#define PACK6(a,b,c,d,e,f) (ENC3(a) | (ENC3(b)<<3) | (ENC3(c)<<6) | \
                            (ENC3(d)<<9) | (ENC3(e)<<12) | (ENC3(f)<<15))
__constant__ unsigned TROW[16] = {
    PACK6(-1,-1,-1,-1,-1,-1), PACK6(1,0,2,-1,-1,-1), PACK6(4,0,3,-1,-1,-1), PACK6(1,4,2,1,3,4),
    PACK6(3,1,5,-1,-1,-1),    PACK6(2,3,0,2,5,3),    PACK6(1,4,0,1,5,4),    PACK6(4,2,5,-1,-1,-1),
    PACK6(4,5,2,-1,-1,-1),    PACK6(4,1,0,4,5,1),    PACK6(3,2,0,3,5,2),    PACK6(1,3,5,-1,-1,-1),
    PACK6(4,1,2,4,3,1),       PACK6(3,0,4,-1,-1,-1), PACK6(2,0,1,-1,-1,-1), PACK6(-1,-1,-1,-1,-1,-1)};

__device__ __forceinline__ int tidx(const float* sdf, int v0, int v1, int v2, int v3) {
    int ti = 0;
    if (sdf[v0] > 0.0f) ti |= 1;
    if (sdf[v1] > 0.0f) ti |= 2;
    if (sdf[v2] > 0.0f) ti |= 4;
    if (sdf[v3] > 0.0f) ti |= 8;
    return ti;
}

// wrapped int32 key (x64-disabled JAX semantics), shifted to unsigned order
__device__ __forceinline__ unsigned skey_of(int a, int b) {
    int ea = a < b ? a : b;
    int eb = a < b ? b : a;
    unsigned ukey = (unsigned)ea * 300000u + (unsigned)eb;   // wraps like int32
    return ukey ^ 0x80000000u;                               // unsigned cmp == signed cmp
}

// K0: ntri + mask outputs, bucket counts, flags
__global__ void k0_count(const int* __restrict__ tets, const float* __restrict__ sdf,
                         unsigned* __restrict__ cnt1, unsigned* __restrict__ flags,
                         float* __restrict__ out_ntri, float* __restrict__ out_mask) {
    int f = blockIdx.x * 256 + threadIdx.x;
    if (f >= NFF) return;
    const int4 tv = ((const int4*)tets)[f];
    int v0 = tv.x, v1 = tv.y, v2 = tv.z, v3 = tv.w;
    int ti = tidx(sdf, v0, v1, v2, v3);
    unsigned row = TROW[ti];
    bool has1 = (row & 7u) != 7u;
    bool has2 = ((row >> 9) & 7u) != 7u;
    int nt = has2 ? 2 : (has1 ? 1 : 0);
    out_ntri[f] = (float)nt;
    out_mask[f * 2 + 0] = has1 ? 1.0f : 0.0f;
    out_mask[f * 2 + 1] = has2 ? 1.0f : 0.0f;
    if (!has1) { atomicOr(&flags[0], 1u); return; }   // ti==0 or 15 -> invalid tet
#define CNT_EDGE(A,B) { unsigned sk_ = skey_of(A, B); \
    if (sk_ == 0x80000000u) atomicOr(&flags[1], 1u); \
    atomicAdd(&cnt1[sk_ >> BSH], 1u); }
    CNT_EDGE(v0, v1) CNT_EDGE(v0, v2) CNT_EDGE(v0, v3)
    CNT_EDGE(v1, v2) CNT_EDGE(v1, v3) CNT_EDGE(v2, v3)
#undef CNT_EDGE
}

// exclusive block scan (Hillis-Steele); bsums optional
__global__ void scan_block(const unsigned* __restrict__ in, unsigned* __restrict__ out,
                           unsigned* __restrict__ bsums, int n) {
    __shared__ unsigned s[1024];
    int tid = threadIdx.x;
    int g = blockIdx.x * 1024 + tid;
    unsigned v = (g < n) ? in[g] : 0u;
    s[tid] = v;
    __syncthreads();
    for (int off = 1; off < 1024; off <<= 1) {
        unsigned t = (tid >= off) ? s[tid - off] : 0u;
        __syncthreads();
        s[tid] += t;
        __syncthreads();
    }
    if (g < n) out[g] = s[tid] - v;  // exclusive
    if (tid == 1023 && bsums) bsums[blockIdx.x] = s[1023];
}

__global__ void scan_add(unsigned* __restrict__ out, const unsigned* __restrict__ ssums,
                         const unsigned* __restrict__ in, unsigned* __restrict__ total, int n) {
    int g = blockIdx.x * 1024 + threadIdx.x;
    if (g >= n) return;
    unsigned v = out[g] + ssums[g >> 10];
    out[g] = v;
    if (g == n - 1) *total = v + in[g];
}

// K1: scatter skeys + origin slots into buckets
__global__ void k1_scatter(const int* __restrict__ tets, const float* __restrict__ sdf,
                           const unsigned* __restrict__ off1, unsigned* __restrict__ cnt2,
                           unsigned* __restrict__ bEb, unsigned* __restrict__ bOrig) {
    int f = blockIdx.x * 256 + threadIdx.x;
    if (f >= NFF) return;
    const int4 tv = ((const int4*)tets)[f];
    int v0 = tv.x, v1 = tv.y, v2 = tv.z, v3 = tv.w;
    int ti = tidx(sdf, v0, v1, v2, v3);
    if (ti == 0 || ti == 15) return;
    unsigned base = (unsigned)f * 6u;
#define SCAT_EDGE(A,B,E) { unsigned sk_ = skey_of(A, B); unsigned b_ = sk_ >> BSH; \
    unsigned p_ = off1[b_] + atomicAdd(&cnt2[b_], 1u); \
    bEb[p_] = sk_; bOrig[p_] = base + (E); }
    SCAT_EDGE(v0, v1, 0u) SCAT_EDGE(v0, v2, 1u) SCAT_EDGE(v0, v3, 2u)
    SCAT_EDGE(v1, v2, 3u) SCAT_EDGE(v1, v3, 4u) SCAT_EDGE(v2, v3, 5u)
#undef SCAT_EDGE
}

// K2: representative = first position in bucket holding its skey; flag in bOrig bit31
__global__ void k2_rep(const unsigned* __restrict__ off1, const unsigned* __restrict__ bEb,
                       unsigned* __restrict__ bOrig, unsigned* __restrict__ dcnt) {
    unsigned p = blockIdx.x * 256 + threadIdx.x;
    unsigned total = off1[NB];
    if (p >= total) return;
    unsigned mySk = bEb[p];
    unsigned b = mySk >> BSH;
    unsigned s = off1[b];
    bool rep = true;
    for (unsigned q = s; q < p; q++) {
        if (bEb[q] == mySk) { rep = false; break; }
    }
    if (rep) {
        bOrig[p] |= 0x80000000u;   // single-owner RMW
        atomicAdd(&dcnt[b], 1u);
    }
}

// decode wrapped int32 key -> gather indices (JAX floor-div + negative wrap)
__device__ __forceinline__ void decode_key(unsigned sk, int* iua, int* iub) {
    int key = (int)(sk ^ 0x80000000u);
    long long kk = (long long)key;
    long long q = kk / 300000LL;
    long long r = kk - q * 300000LL;
    if (r < 0) { q -= 1; r += 300000LL; }
    int ua = (int)q;
    if (ua < 0) ua += NVV;       // JAX negative-index wrap
    *iua = ua;
    *iub = (int)r;
}

// K3: ALL positions compute distinct rank -> idx_map; reps also write verts/cross
__global__ void k3_all(const float* __restrict__ pos, const float* __restrict__ sdf,
                       const unsigned* __restrict__ off1, const unsigned* __restrict__ bEb,
                       const unsigned* __restrict__ bOrig,
                       const unsigned* __restrict__ base2, const unsigned* __restrict__ flags,
                       unsigned* __restrict__ idx_map,
                       float* __restrict__ out_verts, float* __restrict__ out_cross) {
    unsigned p = blockIdx.x * 256 + threadIdx.x;
    unsigned total = off1[NB];
    if (p >= total) return;
    unsigned mySk = bEb[p];
    unsigned b = mySk >> BSH;
    unsigned s = off1[b], e = off1[b + 1];
    unsigned rank = 0;
    for (unsigned q = s; q < e; q++) {
        if (bEb[q] < mySk && (bOrig[q] >> 31)) rank++;
    }
    bool needZ = (flags[0] && !flags[1]);
    unsigned g = base2[b] + rank + ((needZ && mySk > 0x80000000u) ? 1u : 0u);
    unsigned og = bOrig[p];
    idx_map[og & 0x7FFFFFFFu] = g;
    if (og >> 31) {
        int ua, ub;
        decode_key(mySk, &ua, &ub);
        float s0 = sdf[ua], s1 = sdf[ub];
        bool cr = (s0 > 0.0f) != (s1 > 0.0f);
        out_cross[g] = cr ? 1.0f : 0.0f;
        if (cr) {
            float denom = s0 - s1;
            float wa = -s1 / denom, wb = s0 / denom;
            out_verts[g * 3 + 0] = wa * pos[ua * 3 + 0] + wb * pos[ub * 3 + 0];
            out_verts[g * 3 + 1] = wa * pos[ua * 3 + 1] + wb * pos[ub * 3 + 1];
            out_verts[g * 3 + 2] = wa * pos[ua * 3 + 2] + wb * pos[ub * 3 + 2];
        }
    }
}

// K5: faces — coalesced gather from idx_map (u32, same buffer), overwrite as float
__global__ void k5_faces(const int* __restrict__ tets, const float* __restrict__ sdf,
                         void* faces_buf) {
    int f = blockIdx.x * 256 + threadIdx.x;
    if (f >= NFF) return;
    const int4 tv = ((const int4*)tets)[f];
    int v0 = tv.x, v1 = tv.y, v2 = tv.z, v3 = tv.w;
    int ti = tidx(sdf, v0, v1, v2, v3);
    unsigned row = TROW[ti];
    bool has1 = (row & 7u) != 7u;
    bool has2 = ((row >> 9) & 7u) != 7u;
    float* of = (float*)faces_buf + (size_t)f * 6;
    if (!has1) {
        of[0] = -1.0f; of[1] = -1.0f; of[2] = -1.0f;
        of[3] = -1.0f; of[4] = -1.0f; of[5] = -1.0f;
        return;
    }
    const unsigned* im = (const unsigned*)faces_buf + (size_t)f * 6;
    float g0 = (float)im[0], g1 = (float)im[1], g2 = (float)im[2];
    float g3 = (float)im[3], g4 = (float)im[4], g5 = (float)im[5];
    unsigned l0 = row & 7u,         l1 = (row >> 3) & 7u,  l2 = (row >> 6) & 7u;
    unsigned l3 = (row >> 9) & 7u,  l4 = (row >> 12) & 7u, l5 = (row >> 15) & 7u;
#define SEL(L) ((L) == 0u ? g0 : (L) == 1u ? g1 : (L) == 2u ? g2 : \
                (L) == 3u ? g3 : (L) == 4u ? g4 : g5)
    float o0 = SEL(l0), o1 = SEL(l1), o2 = SEL(l2);
    float o3 = has2 ? SEL(l3) : -1.0f;
    float o4 = has2 ? SEL(l4) : -1.0f;
    float o5 = has2 ? SEL(l5) : -1.0f;
#undef SEL
    of[0] = o0; of[1] = o1; of[2] = o2;
    of[3] = o3; of[4] = o4; of[5] = o5;
}

// K6: uv atlas — runs LAST over the uvs region (was bEb/counters scratch)
__global__ void k6_uvs(float* __restrict__ out_uvs) {
    int c = blockIdx.x * 256 + threadIdx.x;
    if (c >= NGRID * NGRID) return;
    int i = c / NGRID, j = c - i * NGRID;
    const float inv = 1.0f / (float)NGRID;
    const float pad = 0.9f / (float)NGRID;
    float x = (float)j * inv;
    float y = (float)i * inv;
    float* o = out_uvs + (size_t)c * 8;
    o[0] = x;       o[1] = y;
    o[2] = x + pad; o[3] = y;
    o[4] = x + pad; o[5] = y + pad;
    o[6] = x;       o[7] = y + pad;
}

// K7: uv_idx — runs LAST over the uv_idx region (was bOrig scratch)
__global__ void k7_uvidx(float* __restrict__ out_uvidx) {
    int f = blockIdx.x * 256 + threadIdx.x;
    if (f >= NFF) return;
    float base = (float)(4 * f);
    float* uvi = out_uvidx + (size_t)f * 6;
    uvi[0] = base; uvi[1] = base + 1.0f; uvi[2] = base + 2.0f;
    uvi[3] = base; uvi[4] = base + 2.0f; uvi[5] = base + 3.0f;
}

extern "C" void kernel_launch(void* const* d_in, const int* in_sizes, int n_in,
                              void* d_out, int out_size, void* d_ws, size_t ws_size,
                              hipStream_t stream) {
    const float* pos = (const float*)d_in[0];
    const float* sdf = (const float*)d_in[1];
    const int* tets = (const int*)d_in[2];
    float* out = (float*)d_out;
    unsigned* u = (unsigned*)d_out;

    unsigned* bEb   = u + S_EB;
    unsigned* bOrig = u + S_ORIG;
    unsigned* cnt1  = u + S_CNT1;
    unsigned* cnt2  = u + S_CNT2;
    unsigned* dcnt  = u + S_DCNT;
    unsigned* flags = u + S_FLAGS;
    unsigned* off1  = u + S_OFF1;
    unsigned* base2 = u + S_BASE2;
    unsigned* bsums = u + S_BSUMS;
    unsigned* ssums = u + S_SSUMS;
    unsigned* idx_map = u + OFF_FACES;

    // zero counters+flags (contiguous), verts, cross (every call — replay-safe)
    hipMemsetAsync(cnt1, 0, (size_t)(3 * NB + 8) * 4, stream);
    hipMemsetAsync(out + OFF_VERTS, 0, (size_t)27000000 * 4, stream);
    hipMemsetAsync(out + OFF_CROSS, 0, (size_t)9000000 * 4, stream);

    dim3 blk(256);
    int gF = (NFF + 255) / 256;
    int gE = (NE + 255) / 256;

    k0_count<<<gF, blk, 0, stream>>>(tets, sdf, cnt1, flags,
                                     out + OFF_NTRI, out + OFF_MASK);

    // scan1: cnt1 -> off1 (+ total at off1[NB])
    const int n = NB, nb = NB / 1024;  // 256 blocks
    scan_block<<<nb, 1024, 0, stream>>>(cnt1, off1, bsums, n);
    scan_block<<<1, 1024, 0, stream>>>(bsums, ssums, nullptr, nb);
    scan_add<<<nb, 1024, 0, stream>>>(off1, ssums, cnt1, off1 + NB, n);

    k1_scatter<<<gF, blk, 0, stream>>>(tets, sdf, off1, cnt2, bEb, bOrig);
    k2_rep<<<gE, blk, 0, stream>>>(off1, bEb, bOrig, dcnt);

    // scan2: dcnt -> base2
    scan_block<<<nb, 1024, 0, stream>>>(dcnt, base2, bsums, n);
    scan_block<<<1, 1024, 0, stream>>>(bsums, ssums, nullptr, nb);
    scan_add<<<nb, 1024, 0, stream>>>(base2, ssums, dcnt, base2 + NB, n);

    k3_all<<<gE, blk, 0, stream>>>(pos, sdf, off1, bEb, bOrig, base2, flags,
                                   idx_map, out + OFF_VERTS, out + OFF_CROSS);
    k5_faces<<<gF, blk, 0, stream>>>(tets, sdf, (void*)(out + OFF_FACES));

    // scratch regions are free now — write the real uvs / uv_idx outputs
    int gC = (NGRID * NGRID + 255) / 256;
    k6_uvs<<<gC, blk, 0, stream>>>(out + OFF_UVS);
    k7_uvidx<<<gF, blk, 0, stream>>>(out + OFF_UVIDX);
}

// Round 7
// 1286.654 us; speedup vs baseline: 6.8881x; 1.3577x over previous
//
#include <hip/hip_runtime.h>
#include <stdint.h>

#define NVV 300000
#define NFF 1500000
#define NE  9000000
#define NGRID 1225
#define NB   262144        // key-space buckets = 2^18
#define BSH  14            // bucket = skey >> BSH
#define BCAP 256           // LDS bucket capacity per wave

// d_out layout (float32 element offsets)
#define OFF_VERTS 0
#define OFF_FACES 27000000
#define OFF_MASK  36000000
#define OFF_NTRI  39000000
#define OFF_CROSS 40500000
#define OFF_UVS   49500000
#define OFF_UVIDX 61505000

// ALL scratch lives in d_out (uvs+uv_idx tail is contiguous: 49.5M..70.505M),
// overwritten with final values LAST. d_ws never used.
#define S_PAIR  49500000u            // bPair: 9,000,000 uint2 (18M u32)
#define S_CNT1  67500000u            // NB
#define S_CNT2  (S_CNT1 + NB)        // NB
#define S_DCNT  (S_CNT2 + NB)        // NB
#define S_FLAGS (S_DCNT + NB)        // 8  [0]=hasInvalid [1]=validZeroKey
#define S_OFF1  (S_FLAGS + 8)        // NB+1
#define S_BASE2 (S_OFF1 + NB + 1)    // NB+1
#define S_BSUMS (S_BASE2 + NB + 1)   // 1024
#define S_SSUMS (S_BSUMS + 1024)     // 1024 (ends 68,812,778 < 70,505,000)
// idx_map: 9,000,000 u32 stored in the faces region (read+overwritten by k5)

// tri table packed: entry e (local edge id 0..5, or 7 for -1) in bits [3e,3e+3)
#define ENC3(x) ((unsigned)(((x) < 0) ? 7 : (x)))
#define PACK6(a,b,c,d,e,f) (ENC3(a) | (ENC3(b)<<3) | (ENC3(c)<<6) | \
                            (ENC3(d)<<9) | (ENC3(e)<<12) | (ENC3(f)<<15))
__constant__ unsigned TROW[16] = {
    PACK6(-1,-1,-1,-1,-1,-1), PACK6(1,0,2,-1,-1,-1), PACK6(4,0,3,-1,-1,-1), PACK6(1,4,2,1,3,4),
    PACK6(3,1,5,-1,-1,-1),    PACK6(2,3,0,2,5,3),    PACK6(1,4,0,1,5,4),    PACK6(4,2,5,-1,-1,-1),
    PACK6(4,5,2,-1,-1,-1),    PACK6(4,1,0,4,5,1),    PACK6(3,2,0,3,5,2),    PACK6(1,3,5,-1,-1,-1),
    PACK6(4,1,2,4,3,1),       PACK6(3,0,4,-1,-1,-1), PACK6(2,0,1,-1,-1,-1), PACK6(-1,-1,-1,-1,-1,-1)};

__device__ __forceinline__ int tidx(const float* sdf, int v0, int v1, int v2, int v3) {
    int ti = 0;
    if (sdf[v0] > 0.0f) ti |= 1;
    if (sdf[v1] > 0.0f) ti |= 2;
    if (sdf[v2] > 0.0f) ti |= 4;
    if (sdf[v3] > 0.0f) ti |= 8;
    return ti;
}

// wrapped int32 key (x64-disabled JAX semantics), shifted to unsigned order
__device__ __forceinline__ unsigned skey_of(int a, int b) {
    int ea = a < b ? a : b;
    int eb = a < b ? b : a;
    unsigned ukey = (unsigned)ea * 300000u + (unsigned)eb;   // wraps like int32
    return ukey ^ 0x80000000u;                               // unsigned cmp == signed cmp
}

// K0: ntri + mask outputs, bucket counts, flags
__global__ void k0_count(const int* __restrict__ tets, const float* __restrict__ sdf,
                         unsigned* __restrict__ cnt1, unsigned* __restrict__ flags,
                         float* __restrict__ out_ntri, float* __restrict__ out_mask) {
    int f = blockIdx.x * 256 + threadIdx.x;
    if (f >= NFF) return;
    const int4 tv = ((const int4*)tets)[f];
    int v0 = tv.x, v1 = tv.y, v2 = tv.z, v3 = tv.w;
    int ti = tidx(sdf, v0, v1, v2, v3);
    unsigned row = TROW[ti];
    bool has1 = (row & 7u) != 7u;
    bool has2 = ((row >> 9) & 7u) != 7u;
    int nt = has2 ? 2 : (has1 ? 1 : 0);
    out_ntri[f] = (float)nt;
    out_mask[f * 2 + 0] = has1 ? 1.0f : 0.0f;
    out_mask[f * 2 + 1] = has2 ? 1.0f : 0.0f;
    if (!has1) { atomicOr(&flags[0], 1u); return; }   // ti==0 or 15 -> invalid tet
#define CNT_EDGE(A,B) { unsigned sk_ = skey_of(A, B); \
    if (sk_ == 0x80000000u) atomicOr(&flags[1], 1u); \
    atomicAdd(&cnt1[sk_ >> BSH], 1u); }
    CNT_EDGE(v0, v1) CNT_EDGE(v0, v2) CNT_EDGE(v0, v3)
    CNT_EDGE(v1, v2) CNT_EDGE(v1, v3) CNT_EDGE(v2, v3)
#undef CNT_EDGE
}

// exclusive block scan (Hillis-Steele); bsums optional
__global__ void scan_block(const unsigned* __restrict__ in, unsigned* __restrict__ out,
                           unsigned* __restrict__ bsums, int n) {
    __shared__ unsigned s[1024];
    int tid = threadIdx.x;
    int g = blockIdx.x * 1024 + tid;
    unsigned v = (g < n) ? in[g] : 0u;
    s[tid] = v;
    __syncthreads();
    for (int off = 1; off < 1024; off <<= 1) {
        unsigned t = (tid >= off) ? s[tid - off] : 0u;
        __syncthreads();
        s[tid] += t;
        __syncthreads();
    }
    if (g < n) out[g] = s[tid] - v;  // exclusive
    if (tid == 1023 && bsums) bsums[blockIdx.x] = s[1023];
}

__global__ void scan_add(unsigned* __restrict__ out, const unsigned* __restrict__ ssums,
                         const unsigned* __restrict__ in, unsigned* __restrict__ total, int n) {
    int g = blockIdx.x * 1024 + threadIdx.x;
    if (g >= n) return;
    unsigned v = out[g] + ssums[g >> 10];
    out[g] = v;
    if (g == n - 1) *total = v + in[g];
}

// K1: scatter {skey, origin} pairs into buckets (single 8B write per edge)
__global__ void k1_scatter(const int* __restrict__ tets, const float* __restrict__ sdf,
                           const unsigned* __restrict__ off1, unsigned* __restrict__ cnt2,
                           uint2* __restrict__ bPair) {
    int f = blockIdx.x * 256 + threadIdx.x;
    if (f >= NFF) return;
    const int4 tv = ((const int4*)tets)[f];
    int v0 = tv.x, v1 = tv.y, v2 = tv.z, v3 = tv.w;
    int ti = tidx(sdf, v0, v1, v2, v3);
    if (ti == 0 || ti == 15) return;
    unsigned base = (unsigned)f * 6u;
#define SCAT_EDGE(A,B,E) { unsigned sk_ = skey_of(A, B); unsigned b_ = sk_ >> BSH; \
    unsigned p_ = off1[b_] + atomicAdd(&cnt2[b_], 1u); \
    bPair[p_] = make_uint2(sk_, base + (E)); }
    SCAT_EDGE(v0, v1, 0u) SCAT_EDGE(v0, v2, 1u) SCAT_EDGE(v0, v3, 2u)
    SCAT_EDGE(v1, v2, 3u) SCAT_EDGE(v1, v3, 4u) SCAT_EDGE(v2, v3, 5u)
#undef SCAT_EDGE
}

// K2: wave-per-bucket distinct count via LDS (no atomics, no RMW)
__global__ void k2_count(const unsigned* __restrict__ off1,
                         const uint2* __restrict__ bPair,
                         unsigned* __restrict__ dcnt) {
    __shared__ unsigned keys[4][BCAP];
    int w = threadIdx.x >> 6, lane = threadIdx.x & 63;
    unsigned b = blockIdx.x * 4u + (unsigned)w;      // grid = NB/4 -> b < NB always
    unsigned s = off1[b], e = off1[b + 1];
    unsigned n = e - s;
    bool ok = (n <= BCAP);
    if (ok) for (unsigned i = lane; i < n; i += 64) keys[w][i] = bPair[s + i].x;
    __syncthreads();
    unsigned cnt = 0;
    if (ok) {
        for (unsigned i = lane; i < n; i += 64) {
            unsigned my = keys[w][i];
            bool rep = true;
            for (unsigned j = 0; j < i; j++)
                if (keys[w][j] == my) { rep = false; break; }
            cnt += rep ? 1u : 0u;
        }
    } else {            // astronomically rare fallback
        for (unsigned i = lane; i < n; i += 64) {
            unsigned my = bPair[s + i].x;
            bool rep = true;
            for (unsigned j = 0; j < i; j++)
                if (bPair[s + j].x == my) { rep = false; break; }
            cnt += rep ? 1u : 0u;
        }
    }
#pragma unroll
    for (int o = 32; o > 0; o >>= 1) cnt += __shfl_down(cnt, o);
    if (lane == 0) dcnt[b] = cnt;
}

// decode wrapped int32 key -> gather indices (JAX floor-div + negative wrap)
__device__ __forceinline__ void decode_key(unsigned sk, int* iua, int* iub) {
    int key = (int)(sk ^ 0x80000000u);
    long long kk = (long long)key;
    long long q = kk / 300000LL;
    long long r = kk - q * 300000LL;
    if (r < 0) { q -= 1; r += 300000LL; }
    int ua = (int)q;
    if (ua < 0) ua += NVV;       // JAX negative-index wrap
    *iua = ua;
    *iub = (int)r;
}

__device__ __forceinline__ void write_vert(unsigned sk, unsigned g,
                                           const float* __restrict__ pos,
                                           const float* __restrict__ sdf,
                                           float* __restrict__ out_verts,
                                           float* __restrict__ out_cross) {
    int ua, ub;
    decode_key(sk, &ua, &ub);
    float s0 = sdf[ua], s1 = sdf[ub];
    bool cr = (s0 > 0.0f) != (s1 > 0.0f);
    out_cross[g] = cr ? 1.0f : 0.0f;
    if (cr) {
        float denom = s0 - s1;
        float wa = -s1 / denom, wb = s0 / denom;
        out_verts[g * 3 + 0] = wa * pos[ua * 3 + 0] + wb * pos[ub * 3 + 0];
        out_verts[g * 3 + 1] = wa * pos[ua * 3 + 1] + wb * pos[ub * 3 + 1];
        out_verts[g * 3 + 2] = wa * pos[ua * 3 + 2] + wb * pos[ub * 3 + 2];
    }
}

// K3: wave-per-bucket ranks via LDS -> idx_map; reps write verts/cross
__global__ void k3_rank(const float* __restrict__ pos, const float* __restrict__ sdf,
                        const unsigned* __restrict__ off1, const uint2* __restrict__ bPair,
                        const unsigned* __restrict__ base2, const unsigned* __restrict__ flags,
                        unsigned* __restrict__ idx_map,
                        float* __restrict__ out_verts, float* __restrict__ out_cross) {
    __shared__ unsigned keys[4][BCAP];
    __shared__ unsigned origs[4][BCAP];
    __shared__ unsigned char repf[4][BCAP];
    int w = threadIdx.x >> 6, lane = threadIdx.x & 63;
    unsigned b = blockIdx.x * 4u + (unsigned)w;
    unsigned s = off1[b], e = off1[b + 1];
    unsigned n = e - s;
    bool ok = (n <= BCAP);
    if (ok) for (unsigned i = lane; i < n; i += 64) {
        uint2 t = bPair[s + i];
        keys[w][i] = t.x;
        origs[w][i] = t.y;
    }
    __syncthreads();
    if (ok) for (unsigned i = lane; i < n; i += 64) {
        unsigned my = keys[w][i];
        unsigned char r = 1;
        for (unsigned j = 0; j < i; j++)
            if (keys[w][j] == my) { r = 0; break; }
        repf[w][i] = r;
    }
    __syncthreads();
    bool needZ = (flags[0] != 0u) && (flags[1] == 0u);
    unsigned bb = base2[b];
    if (ok) {
        for (unsigned i = lane; i < n; i += 64) {
            unsigned my = keys[w][i];
            unsigned rank = 0;
            for (unsigned j = 0; j < n; j++)
                rank += (repf[w][j] && keys[w][j] < my) ? 1u : 0u;
            unsigned g = bb + rank + ((needZ && my > 0x80000000u) ? 1u : 0u);
            idx_map[origs[w][i]] = g;
            if (repf[w][i]) write_vert(my, g, pos, sdf, out_verts, out_cross);
        }
    } else {            // astronomically rare fallback (O(n^3), correctness only)
        for (unsigned i = lane; i < n; i += 64) {
            unsigned my = bPair[s + i].x;
            bool isrep = true;
            for (unsigned j = 0; j < i; j++)
                if (bPair[s + j].x == my) { isrep = false; break; }
            unsigned rank = 0;
            for (unsigned j = 0; j < n; j++) {
                unsigned kj = bPair[s + j].x;
                if (kj < my) {
                    bool jr = true;
                    for (unsigned k = 0; k < j; k++)
                        if (bPair[s + k].x == kj) { jr = false; break; }
                    rank += jr ? 1u : 0u;
                }
            }
            unsigned g = bb + rank + ((needZ && my > 0x80000000u) ? 1u : 0u);
            idx_map[bPair[s + i].y] = g;
            if (isrep) write_vert(my, g, pos, sdf, out_verts, out_cross);
        }
    }
}

// K5: faces — coalesced gather from idx_map (u32, same buffer), overwrite as float
__global__ void k5_faces(const int* __restrict__ tets, const float* __restrict__ sdf,
                         void* faces_buf) {
    int f = blockIdx.x * 256 + threadIdx.x;
    if (f >= NFF) return;
    const int4 tv = ((const int4*)tets)[f];
    int v0 = tv.x, v1 = tv.y, v2 = tv.z, v3 = tv.w;
    int ti = tidx(sdf, v0, v1, v2, v3);
    unsigned row = TROW[ti];
    bool has1 = (row & 7u) != 7u;
    bool has2 = ((row >> 9) & 7u) != 7u;
    float* of = (float*)faces_buf + (size_t)f * 6;
    if (!has1) {
        of[0] = -1.0f; of[1] = -1.0f; of[2] = -1.0f;
        of[3] = -1.0f; of[4] = -1.0f; of[5] = -1.0f;
        return;
    }
    const unsigned* im = (const unsigned*)faces_buf + (size_t)f * 6;
    float g0 = (float)im[0], g1 = (float)im[1], g2 = (float)im[2];
    float g3 = (float)im[3], g4 = (float)im[4], g5 = (float)im[5];
    unsigned l0 = row & 7u,         l1 = (row >> 3) & 7u,  l2 = (row >> 6) & 7u;
    unsigned l3 = (row >> 9) & 7u,  l4 = (row >> 12) & 7u, l5 = (row >> 15) & 7u;
#define SEL(L) ((L) == 0u ? g0 : (L) == 1u ? g1 : (L) == 2u ? g2 : \
                (L) == 3u ? g3 : (L) == 4u ? g4 : g5)
    float o0 = SEL(l0), o1 = SEL(l1), o2 = SEL(l2);
    float o3 = has2 ? SEL(l3) : -1.0f;
    float o4 = has2 ? SEL(l4) : -1.0f;
    float o5 = has2 ? SEL(l5) : -1.0f;
#undef SEL
    of[0] = o0; of[1] = o1; of[2] = o2;
    of[3] = o3; of[4] = o4; of[5] = o5;
}

// K6: uv atlas — runs LAST over the uvs region (was bPair scratch)
__global__ void k6_uvs(float* __restrict__ out_uvs) {
    int c = blockIdx.x * 256 + threadIdx.x;
    if (c >= NGRID * NGRID) return;
    int i = c / NGRID, j = c - i * NGRID;
    const float inv = 1.0f / (float)NGRID;
    const float pad = 0.9f / (float)NGRID;
    float x = (float)j * inv;
    float y = (float)i * inv;
    float* o = out_uvs + (size_t)c * 8;
    o[0] = x;       o[1] = y;
    o[2] = x + pad; o[3] = y;
    o[4] = x + pad; o[5] = y + pad;
    o[6] = x;       o[7] = y + pad;
}

// K7: uv_idx — runs LAST over the uv_idx region (was bPair/counters scratch)
__global__ void k7_uvidx(float* __restrict__ out_uvidx) {
    int f = blockIdx.x * 256 + threadIdx.x;
    if (f >= NFF) return;
    float base = (float)(4 * f);
    float* uvi = out_uvidx + (size_t)f * 6;
    uvi[0] = base; uvi[1] = base + 1.0f; uvi[2] = base + 2.0f;
    uvi[3] = base; uvi[4] = base + 2.0f; uvi[5] = base + 3.0f;
}

extern "C" void kernel_launch(void* const* d_in, const int* in_sizes, int n_in,
                              void* d_out, int out_size, void* d_ws, size_t ws_size,
                              hipStream_t stream) {
    const float* pos = (const float*)d_in[0];
    const float* sdf = (const float*)d_in[1];
    const int* tets = (const int*)d_in[2];
    float* out = (float*)d_out;
    unsigned* u = (unsigned*)d_out;

    uint2*    bPair = (uint2*)(u + S_PAIR);
    unsigned* cnt1  = u + S_CNT1;
    unsigned* cnt2  = u + S_CNT2;
    unsigned* dcnt  = u + S_DCNT;
    unsigned* flags = u + S_FLAGS;
    unsigned* off1  = u + S_OFF1;
    unsigned* base2 = u + S_BASE2;
    unsigned* bsums = u + S_BSUMS;
    unsigned* ssums = u + S_SSUMS;
    unsigned* idx_map = u + OFF_FACES;

    // zero counters+flags (contiguous), verts, cross (every call — replay-safe)
    hipMemsetAsync(cnt1, 0, (size_t)(3 * NB + 8) * 4, stream);
    hipMemsetAsync(out + OFF_VERTS, 0, (size_t)27000000 * 4, stream);
    hipMemsetAsync(out + OFF_CROSS, 0, (size_t)9000000 * 4, stream);

    dim3 blk(256);
    int gF = (NFF + 255) / 256;
    int gB = NB / 4;                  // wave-per-bucket kernels

    k0_count<<<gF, blk, 0, stream>>>(tets, sdf, cnt1, flags,
                                     out + OFF_NTRI, out + OFF_MASK);

    // scan1: cnt1 -> off1 (+ total at off1[NB])
    const int n = NB, nb = NB / 1024;  // 256 blocks
    scan_block<<<nb, 1024, 0, stream>>>(cnt1, off1, bsums, n);
    scan_block<<<1, 1024, 0, stream>>>(bsums, ssums, nullptr, nb);
    scan_add<<<nb, 1024, 0, stream>>>(off1, ssums, cnt1, off1 + NB, n);

    k1_scatter<<<gF, blk, 0, stream>>>(tets, sdf, off1, cnt2, bPair);
    k2_count<<<gB, blk, 0, stream>>>(off1, bPair, dcnt);

    // scan2: dcnt -> base2
    scan_block<<<nb, 1024, 0, stream>>>(dcnt, base2, bsums, n);
    scan_block<<<1, 1024, 0, stream>>>(bsums, ssums, nullptr, nb);
    scan_add<<<nb, 1024, 0, stream>>>(base2, ssums, dcnt, base2 + NB, n);

    k3_rank<<<gB, blk, 0, stream>>>(pos, sdf, off1, bPair, base2, flags,
                                    idx_map, out + OFF_VERTS, out + OFF_CROSS);
    k5_faces<<<gF, blk, 0, stream>>>(tets, sdf, (void*)(out + OFF_FACES));

    // scratch regions are free now — write the real uvs / uv_idx outputs
    int gC = (NGRID * NGRID + 255) / 256;
    k6_uvs<<<gC, blk, 0, stream>>>(out + OFF_UVS);
    k7_uvidx<<<gF, blk, 0, stream>>>(out + OFF_UVIDX);
}

// Round 8
// 1128.330 us; speedup vs baseline: 7.8546x; 1.1403x over previous
//
#include <hip/hip_runtime.h>
#include <stdint.h>

#define NVV 300000
#define NFF 1500000
#define NE  9000000
#define NGRID 1225
#define NB   262144        // key-space buckets = 2^18
#define BSH  14            // bucket = skey >> BSH
#define BCAP 256           // LDS bucket capacity per wave

// d_out layout (float32 element offsets)
#define OFF_VERTS 0
#define OFF_FACES 27000000
#define OFF_MASK  36000000
#define OFF_NTRI  39000000
#define OFF_CROSS 40500000
#define OFF_UVS   49500000
#define OFF_UVIDX 61505000

// ALL scratch lives in d_out. bPair+counters in the contiguous uvs+uv_idx tail
// (49.5M..70.505M els), finalized last. eIdx/idx_map time-share the faces
// region (eIdx: k0->k1 dead after k1; idx_map: k3->k5). d_ws never used.
#define S_PAIR  49500000u            // bPair: 9,000,000 uint2 (18M u32)
#define S_CNT1  67500000u            // NB
#define S_DCNT  (S_CNT1 + NB)        // NB
#define S_FLAGS (S_DCNT + NB)        // 8  [0]=hasInvalid [1]=validZeroKey
#define S_OFF1  (S_FLAGS + 8)        // NB+1
#define S_BASE2 (S_OFF1 + NB + 1)    // NB+1
#define S_BSUMS (S_BASE2 + NB + 1)   // 1024
#define S_SSUMS (S_BSUMS + 1024)     // 1024 (ends ~68.55M < 70.505M)

// tri table packed: entry e (local edge id 0..5, or 7 for -1) in bits [3e,3e+3)
#define ENC3(x) ((unsigned)(((x) < 0) ? 7 : (x)))
#define PACK6(a,b,c,d,e,f) (ENC3(a) | (ENC3(b)<<3) | (ENC3(c)<<6) | \
                            (ENC3(d)<<9) | (ENC3(e)<<12) | (ENC3(f)<<15))
__constant__ unsigned TROW[16] = {
    PACK6(-1,-1,-1,-1,-1,-1), PACK6(1,0,2,-1,-1,-1), PACK6(4,0,3,-1,-1,-1), PACK6(1,4,2,1,3,4),
    PACK6(3,1,5,-1,-1,-1),    PACK6(2,3,0,2,5,3),    PACK6(1,4,0,1,5,4),    PACK6(4,2,5,-1,-1,-1),
    PACK6(4,5,2,-1,-1,-1),    PACK6(4,1,0,4,5,1),    PACK6(3,2,0,3,5,2),    PACK6(1,3,5,-1,-1,-1),
    PACK6(4,1,2,4,3,1),       PACK6(3,0,4,-1,-1,-1), PACK6(2,0,1,-1,-1,-1), PACK6(-1,-1,-1,-1,-1,-1)};

__device__ __forceinline__ int tidx(const float* sdf, int v0, int v1, int v2, int v3) {
    int ti = 0;
    if (sdf[v0] > 0.0f) ti |= 1;
    if (sdf[v1] > 0.0f) ti |= 2;
    if (sdf[v2] > 0.0f) ti |= 4;
    if (sdf[v3] > 0.0f) ti |= 8;
    return ti;
}

// wrapped int32 key (x64-disabled JAX semantics), shifted to unsigned order
__device__ __forceinline__ unsigned skey_of(int a, int b) {
    int ea = a < b ? a : b;
    int eb = a < b ? b : a;
    unsigned ukey = (unsigned)ea * 300000u + (unsigned)eb;   // wraps like int32
    return ukey ^ 0x80000000u;                               // unsigned cmp == signed cmp
}

// K0: ntri/mask outputs, bucket counts WITH returned within-bucket index -> eIdx
__global__ void k0_count(const int* __restrict__ tets, const float* __restrict__ sdf,
                         unsigned* __restrict__ cnt1, unsigned* __restrict__ flags,
                         float* __restrict__ out_ntri, float* __restrict__ out_mask,
                         unsigned* __restrict__ eIdx) {
    int f = blockIdx.x * 256 + threadIdx.x;
    bool live = (f < NFF);
    int fc = live ? f : 0;
    const int4 tv = ((const int4*)tets)[fc];
    int v0 = tv.x, v1 = tv.y, v2 = tv.z, v3 = tv.w;
    int ti = tidx(sdf, v0, v1, v2, v3);
    unsigned row = TROW[ti];
    bool has1 = (row & 7u) != 7u;
    bool has2 = ((row >> 9) & 7u) != 7u;
    if (live) {
        out_ntri[f] = has2 ? 2.0f : (has1 ? 1.0f : 0.0f);
        ((float2*)out_mask)[f] = make_float2(has1 ? 1.0f : 0.0f, has2 ? 1.0f : 0.0f);
    }
    bool valid = live && has1;
    bool z = false;
    if (valid) {
        unsigned sk0 = skey_of(v0, v1), sk1 = skey_of(v0, v2), sk2 = skey_of(v0, v3);
        unsigned sk3 = skey_of(v1, v2), sk4 = skey_of(v1, v3), sk5 = skey_of(v2, v3);
        z = (sk0 == 0x80000000u) | (sk1 == 0x80000000u) | (sk2 == 0x80000000u) |
            (sk3 == 0x80000000u) | (sk4 == 0x80000000u) | (sk5 == 0x80000000u);
        unsigned r0 = atomicAdd(&cnt1[sk0 >> BSH], 1u);
        unsigned r1 = atomicAdd(&cnt1[sk1 >> BSH], 1u);
        unsigned r2 = atomicAdd(&cnt1[sk2 >> BSH], 1u);
        unsigned r3 = atomicAdd(&cnt1[sk3 >> BSH], 1u);
        unsigned r4 = atomicAdd(&cnt1[sk4 >> BSH], 1u);
        unsigned r5 = atomicAdd(&cnt1[sk5 >> BSH], 1u);
        uint2* ep = (uint2*)(eIdx + (size_t)f * 6);   // f*24B, 8B-aligned
        ep[0] = make_uint2(r0, r1);
        ep[1] = make_uint2(r2, r3);
        ep[2] = make_uint2(r4, r5);
    }
    // wave-aggregated flag atomics (no divergent returns above -> all lanes here)
    unsigned long long invb = __ballot(live && !has1);
    unsigned long long zb = __ballot(z);
    if ((threadIdx.x & 63) == 0) {
        if (invb) atomicOr(&flags[0], 1u);
        if (zb) atomicOr(&flags[1], 1u);
    }
}

// exclusive block scan (Hillis-Steele); bsums optional
__global__ void scan_block(const unsigned* __restrict__ in, unsigned* __restrict__ out,
                           unsigned* __restrict__ bsums, int n) {
    __shared__ unsigned s[1024];
    int tid = threadIdx.x;
    int g = blockIdx.x * 1024 + tid;
    unsigned v = (g < n) ? in[g] : 0u;
    s[tid] = v;
    __syncthreads();
    for (int off = 1; off < 1024; off <<= 1) {
        unsigned t = (tid >= off) ? s[tid - off] : 0u;
        __syncthreads();
        s[tid] += t;
        __syncthreads();
    }
    if (g < n) out[g] = s[tid] - v;  // exclusive
    if (tid == 1023 && bsums) bsums[blockIdx.x] = s[1023];
}

__global__ void scan_add(unsigned* __restrict__ out, const unsigned* __restrict__ ssums,
                         const unsigned* __restrict__ in, unsigned* __restrict__ total, int n) {
    int g = blockIdx.x * 1024 + threadIdx.x;
    if (g >= n) return;
    unsigned v = out[g] + ssums[g >> 10];
    out[g] = v;
    if (g == n - 1) *total = v + in[g];
}

// K1: scatter {skey, origin} pairs — NO atomics (position from eIdx)
__global__ void k1_scatter(const int* __restrict__ tets, const float* __restrict__ sdf,
                           const unsigned* __restrict__ off1,
                           const unsigned* __restrict__ eIdx,
                           uint2* __restrict__ bPair) {
    int f = blockIdx.x * 256 + threadIdx.x;
    if (f >= NFF) return;
    const int4 tv = ((const int4*)tets)[f];
    int v0 = tv.x, v1 = tv.y, v2 = tv.z, v3 = tv.w;
    int ti = tidx(sdf, v0, v1, v2, v3);
    if (ti == 0 || ti == 15) return;
    unsigned base = (unsigned)f * 6u;
    const uint2* ep = (const uint2*)(eIdx + (size_t)f * 6);
    uint2 e01 = ep[0], e23 = ep[1], e45 = ep[2];
#define SCAT_EDGE(A,B,E,R) { unsigned sk_ = skey_of(A, B); \
    unsigned p_ = off1[sk_ >> BSH] + (R); \
    bPair[p_] = make_uint2(sk_, base + (E)); }
    SCAT_EDGE(v0, v1, 0u, e01.x) SCAT_EDGE(v0, v2, 1u, e01.y) SCAT_EDGE(v0, v3, 2u, e23.x)
    SCAT_EDGE(v1, v2, 3u, e23.y) SCAT_EDGE(v1, v3, 4u, e45.x) SCAT_EDGE(v2, v3, 5u, e45.y)
#undef SCAT_EDGE
}

// K2: wave-per-bucket distinct count via LDS (no atomics, no RMW)
__global__ void k2_count(const unsigned* __restrict__ off1,
                         const uint2* __restrict__ bPair,
                         unsigned* __restrict__ dcnt) {
    __shared__ unsigned keys[4][BCAP];
    int w = threadIdx.x >> 6, lane = threadIdx.x & 63;
    unsigned b = blockIdx.x * 4u + (unsigned)w;      // grid = NB/4 -> b < NB always
    unsigned s = off1[b], e = off1[b + 1];
    unsigned n = e - s;
    bool ok = (n <= BCAP);
    if (ok) for (unsigned i = lane; i < n; i += 64) keys[w][i] = bPair[s + i].x;
    __syncthreads();
    unsigned cnt = 0;
    if (ok) {
        for (unsigned i = lane; i < n; i += 64) {
            unsigned my = keys[w][i];
            bool rep = true;
            for (unsigned j = 0; j < i; j++)
                if (keys[w][j] == my) { rep = false; break; }
            cnt += rep ? 1u : 0u;
        }
    } else {            // astronomically rare fallback
        for (unsigned i = lane; i < n; i += 64) {
            unsigned my = bPair[s + i].x;
            bool rep = true;
            for (unsigned j = 0; j < i; j++)
                if (bPair[s + j].x == my) { rep = false; break; }
            cnt += rep ? 1u : 0u;
        }
    }
#pragma unroll
    for (int o = 32; o > 0; o >>= 1) cnt += __shfl_down(cnt, o);
    if (lane == 0) dcnt[b] = cnt;
}

// decode wrapped int32 key -> gather indices (JAX floor-div + negative wrap)
__device__ __forceinline__ void decode_key(unsigned sk, int* iua, int* iub) {
    int key = (int)(sk ^ 0x80000000u);
    long long kk = (long long)key;
    long long q = kk / 300000LL;
    long long r = kk - q * 300000LL;
    if (r < 0) { q -= 1; r += 300000LL; }
    int ua = (int)q;
    if (ua < 0) ua += NVV;       // JAX negative-index wrap
    *iua = ua;
    *iub = (int)r;
}

__device__ __forceinline__ void write_vert(unsigned sk, unsigned g,
                                           const float* __restrict__ pos,
                                           const float* __restrict__ sdf,
                                           float* __restrict__ out_verts,
                                           float* __restrict__ out_cross) {
    int ua, ub;
    decode_key(sk, &ua, &ub);
    float s0 = sdf[ua], s1 = sdf[ub];
    bool cr = (s0 > 0.0f) != (s1 > 0.0f);
    out_cross[g] = cr ? 1.0f : 0.0f;
    if (cr) {
        float denom = s0 - s1;
        float wa = -s1 / denom, wb = s0 / denom;
        out_verts[g * 3 + 0] = wa * pos[ua * 3 + 0] + wb * pos[ub * 3 + 0];
        out_verts[g * 3 + 1] = wa * pos[ua * 3 + 1] + wb * pos[ub * 3 + 1];
        out_verts[g * 3 + 2] = wa * pos[ua * 3 + 2] + wb * pos[ub * 3 + 2];
    }
}

// K3: wave-per-bucket ranks via LDS -> idx_map; reps write verts/cross
__global__ void k3_rank(const float* __restrict__ pos, const float* __restrict__ sdf,
                        const unsigned* __restrict__ off1, const uint2* __restrict__ bPair,
                        const unsigned* __restrict__ base2, const unsigned* __restrict__ flags,
                        unsigned* __restrict__ idx_map,
                        float* __restrict__ out_verts, float* __restrict__ out_cross) {
    __shared__ unsigned keys[4][BCAP];
    __shared__ unsigned origs[4][BCAP];
    __shared__ unsigned char repf[4][BCAP];
    int w = threadIdx.x >> 6, lane = threadIdx.x & 63;
    unsigned b = blockIdx.x * 4u + (unsigned)w;
    unsigned s = off1[b], e = off1[b + 1];
    unsigned n = e - s;
    bool ok = (n <= BCAP);
    if (ok) for (unsigned i = lane; i < n; i += 64) {
        uint2 t = bPair[s + i];
        keys[w][i] = t.x;
        origs[w][i] = t.y;
    }
    __syncthreads();
    if (ok) for (unsigned i = lane; i < n; i += 64) {
        unsigned my = keys[w][i];
        unsigned char r = 1;
        for (unsigned j = 0; j < i; j++)
            if (keys[w][j] == my) { r = 0; break; }
        repf[w][i] = r;
    }
    __syncthreads();
    bool needZ = (flags[0] != 0u) && (flags[1] == 0u);
    unsigned bb = base2[b];
    if (ok) {
        for (unsigned i = lane; i < n; i += 64) {
            unsigned my = keys[w][i];
            unsigned rank = 0;
            for (unsigned j = 0; j < n; j++)
                rank += (repf[w][j] && keys[w][j] < my) ? 1u : 0u;
            unsigned g = bb + rank + ((needZ && my > 0x80000000u) ? 1u : 0u);
            idx_map[origs[w][i]] = g;
            if (repf[w][i]) write_vert(my, g, pos, sdf, out_verts, out_cross);
        }
    } else {            // astronomically rare fallback (O(n^3), correctness only)
        for (unsigned i = lane; i < n; i += 64) {
            unsigned my = bPair[s + i].x;
            bool isrep = true;
            for (unsigned j = 0; j < i; j++)
                if (bPair[s + j].x == my) { isrep = false; break; }
            unsigned rank = 0;
            for (unsigned j = 0; j < n; j++) {
                unsigned kj = bPair[s + j].x;
                if (kj < my) {
                    bool jr = true;
                    for (unsigned k = 0; k < j; k++)
                        if (bPair[s + k].x == kj) { jr = false; break; }
                    rank += jr ? 1u : 0u;
                }
            }
            unsigned g = bb + rank + ((needZ && my > 0x80000000u) ? 1u : 0u);
            idx_map[bPair[s + i].y] = g;
            if (isrep) write_vert(my, g, pos, sdf, out_verts, out_cross);
        }
    }
}

// K5: faces — coalesced gather from idx_map (u32, same buffer), overwrite as float
__global__ void k5_faces(const int* __restrict__ tets, const float* __restrict__ sdf,
                         void* faces_buf) {
    int f = blockIdx.x * 256 + threadIdx.x;
    if (f >= NFF) return;
    const int4 tv = ((const int4*)tets)[f];
    int v0 = tv.x, v1 = tv.y, v2 = tv.z, v3 = tv.w;
    int ti = tidx(sdf, v0, v1, v2, v3);
    unsigned row = TROW[ti];
    bool has1 = (row & 7u) != 7u;
    bool has2 = ((row >> 9) & 7u) != 7u;
    float* of = (float*)faces_buf + (size_t)f * 6;
    if (!has1) {
        of[0] = -1.0f; of[1] = -1.0f; of[2] = -1.0f;
        of[3] = -1.0f; of[4] = -1.0f; of[5] = -1.0f;
        return;
    }
    const unsigned* im = (const unsigned*)faces_buf + (size_t)f * 6;
    float g0 = (float)im[0], g1 = (float)im[1], g2 = (float)im[2];
    float g3 = (float)im[3], g4 = (float)im[4], g5 = (float)im[5];
    unsigned l0 = row & 7u,         l1 = (row >> 3) & 7u,  l2 = (row >> 6) & 7u;
    unsigned l3 = (row >> 9) & 7u,  l4 = (row >> 12) & 7u, l5 = (row >> 15) & 7u;
#define SEL(L) ((L) == 0u ? g0 : (L) == 1u ? g1 : (L) == 2u ? g2 : \
                (L) == 3u ? g3 : (L) == 4u ? g4 : g5)
    float o0 = SEL(l0), o1 = SEL(l1), o2 = SEL(l2);
    float o3 = has2 ? SEL(l3) : -1.0f;
    float o4 = has2 ? SEL(l4) : -1.0f;
    float o5 = has2 ? SEL(l5) : -1.0f;
#undef SEL
    of[0] = o0; of[1] = o1; of[2] = o2;
    of[3] = o3; of[4] = o4; of[5] = o5;
}

// K6: uv atlas — runs LAST over the uvs region (was bPair scratch)
__global__ void k6_uvs(float* __restrict__ out_uvs) {
    int c = blockIdx.x * 256 + threadIdx.x;
    if (c >= NGRID * NGRID) return;
    int i = c / NGRID, j = c - i * NGRID;
    const float inv = 1.0f / (float)NGRID;
    const float pad = 0.9f / (float)NGRID;
    float x = (float)j * inv;
    float y = (float)i * inv;
    float4* o = (float4*)(out_uvs + (size_t)c * 8);
    o[0] = make_float4(x, y, x + pad, y);
    o[1] = make_float4(x + pad, y + pad, x, y + pad);
}

// K7: uv_idx — runs LAST over the uv_idx region (was counters scratch)
__global__ void k7_uvidx(float* __restrict__ out_uvidx) {
    int f = blockIdx.x * 256 + threadIdx.x;
    if (f >= NFF) return;
    float base = (float)(4 * f);
    float2* uvi = (float2*)(out_uvidx + (size_t)f * 6);
    uvi[0] = make_float2(base, base + 1.0f);
    uvi[1] = make_float2(base + 2.0f, base);
    uvi[2] = make_float2(base + 2.0f, base + 3.0f);
}

extern "C" void kernel_launch(void* const* d_in, const int* in_sizes, int n_in,
                              void* d_out, int out_size, void* d_ws, size_t ws_size,
                              hipStream_t stream) {
    const float* pos = (const float*)d_in[0];
    const float* sdf = (const float*)d_in[1];
    const int* tets = (const int*)d_in[2];
    float* out = (float*)d_out;
    unsigned* u = (unsigned*)d_out;

    uint2*    bPair = (uint2*)(u + S_PAIR);
    unsigned* cnt1  = u + S_CNT1;
    unsigned* dcnt  = u + S_DCNT;
    unsigned* flags = u + S_FLAGS;
    unsigned* off1  = u + S_OFF1;
    unsigned* base2 = u + S_BASE2;
    unsigned* bsums = u + S_BSUMS;
    unsigned* ssums = u + S_SSUMS;
    unsigned* eIdx    = u + OFF_FACES;   // k0 -> k1 (dead after k1)
    unsigned* idx_map = u + OFF_FACES;   // k3 -> k5 (same region, sequential reuse)

    // zero counters+flags (contiguous: cnt1,dcnt,flags), verts, cross
    hipMemsetAsync(cnt1, 0, (size_t)(2 * NB + 8) * 4, stream);
    hipMemsetAsync(out + OFF_VERTS, 0, (size_t)27000000 * 4, stream);
    hipMemsetAsync(out + OFF_CROSS, 0, (size_t)9000000 * 4, stream);

    dim3 blk(256);
    int gF = (NFF + 255) / 256;
    int gB = NB / 4;                  // wave-per-bucket kernels

    k0_count<<<gF, blk, 0, stream>>>(tets, sdf, cnt1, flags,
                                     out + OFF_NTRI, out + OFF_MASK, eIdx);

    // scan1: cnt1 -> off1 (+ total at off1[NB])
    const int n = NB, nb = NB / 1024;  // 256 blocks
    scan_block<<<nb, 1024, 0, stream>>>(cnt1, off1, bsums, n);
    scan_block<<<1, 1024, 0, stream>>>(bsums, ssums, nullptr, nb);
    scan_add<<<nb, 1024, 0, stream>>>(off1, ssums, cnt1, off1 + NB, n);

    k1_scatter<<<gF, blk, 0, stream>>>(tets, sdf, off1, eIdx, bPair);
    k2_count<<<gB, blk, 0, stream>>>(off1, bPair, dcnt);

    // scan2: dcnt -> base2
    scan_block<<<nb, 1024, 0, stream>>>(dcnt, base2, bsums, n);
    scan_block<<<1, 1024, 0, stream>>>(bsums, ssums, nullptr, nb);
    scan_add<<<nb, 1024, 0, stream>>>(base2, ssums, dcnt, base2 + NB, n);

    k3_rank<<<gB, blk, 0, stream>>>(pos, sdf, off1, bPair, base2, flags,
                                    idx_map, out + OFF_VERTS, out + OFF_CROSS);
    k5_faces<<<gF, blk, 0, stream>>>(tets, sdf, (void*)(out + OFF_FACES));

    // scratch regions are free now — write the real uvs / uv_idx outputs
    int gC = (NGRID * NGRID + 255) / 256;
    k6_uvs<<<gC, blk, 0, stream>>>(out + OFF_UVS);
    k7_uvidx<<<gF, blk, 0, stream>>>(out + OFF_UVIDX);
}

// Round 10
// 777.186 us; speedup vs baseline: 11.4035x; 1.4518x over previous
//
#include <hip/hip_runtime.h>
#include <stdint.h>

#define NVV 300000
#define NFF 1500000
#define NE  9000000
#define NGRID 1225
#define NB   262144        // key-space buckets = 2^18 (fine)
#define BSH  14            // fine bucket = skey >> BSH
#define BCAP 256           // LDS bucket capacity per wave (k2/k3)
#define NC   512           // coarse bins
#define CSH  23            // coarse bin = skey >> CSH
#define NF2  512           // fine bins per coarse
#define NBLK1 2048         // blocks for kA/kB
#define NHIST (NC * NBLK1) // 1,048,576

// d_out layout (float32 element offsets)
#define OFF_VERTS 0
#define OFF_FACES 27000000
#define OFF_MASK  36000000
#define OFF_NTRI  39000000
#define OFF_CROSS 40500000
#define OFF_UVS   49500000
#define OFF_UVIDX 61505000

// ALL scratch lives in d_out; d_ws never used.
// tail (49.5M..70.505M u32):
#define S_PAIR  49500000u                  // bPair: 9M uint2 = 18M u32 -> 67.5M
#define S_GH    67500000u                  // gHist: 1,048,576
#define S_GS    (S_GH + NHIST)             // gScan: 1,048,576 -> 69,597,152
#define S_DCNT  (S_GS + NHIST)             // NB -> 69,859,296
#define S_OFF1  (S_DCNT + NB)              // NB+1 -> 70,121,441
#define S_BASE2 (S_OFF1 + NB + 1)          // NB+1 -> 70,383,586
#define S_BSUMS (S_BASE2 + NB + 1)         // 1024
#define S_SSUMS (S_BSUMS + 1024)           // 1024
#define S_FLG   (S_SSUMS + 1024)           // 8 -> ends 70,385,642 < 70,505,000
// staging: 9M uint2 = 72MB in the verts region (108MB), memset after kC
// idx_map: 9M u32 in the faces region (k3 -> k5)

// tri table packed: entry e (local edge id 0..5, or 7 for -1) in bits [3e,3e+3)
#define ENC3(x) ((unsigned)(((x) < 0) ? 7 : (x)))
#define PACK6(a,b,c,d,e,f) (ENC3(a) | (ENC3(b)<<3) | (ENC3(c)<<6) | \
                            (ENC3(d)<<9) | (ENC3(e)<<12) | (ENC3(f)<<15))
__constant__ unsigned TROW[16] = {
    PACK6(-1,-1,-1,-1,-1,-1), PACK6(1,0,2,-1,-1,-1), PACK6(4,0,3,-1,-1,-1), PACK6(1,4,2,1,3,4),
    PACK6(3,1,5,-1,-1,-1),    PACK6(2,3,0,2,5,3),    PACK6(1,4,0,1,5,4),    PACK6(4,2,5,-1,-1,-1),
    PACK6(4,5,2,-1,-1,-1),    PACK6(4,1,0,4,5,1),    PACK6(3,2,0,3,5,2),    PACK6(1,3,5,-1,-1,-1),
    PACK6(4,1,2,4,3,1),       PACK6(3,0,4,-1,-1,-1), PACK6(2,0,1,-1,-1,-1), PACK6(-1,-1,-1,-1,-1,-1)};

__device__ __forceinline__ int tidx(const float* sdf, int v0, int v1, int v2, int v3) {
    int ti = 0;
    if (sdf[v0] > 0.0f) ti |= 1;
    if (sdf[v1] > 0.0f) ti |= 2;
    if (sdf[v2] > 0.0f) ti |= 4;
    if (sdf[v3] > 0.0f) ti |= 8;
    return ti;
}

// wrapped int32 key (x64-disabled JAX semantics), shifted to unsigned order
__device__ __forceinline__ unsigned skey_of(int a, int b) {
    int ea = a < b ? a : b;
    int eb = a < b ? b : a;
    unsigned ukey = (unsigned)ea * 300000u + (unsigned)eb;   // wraps like int32
    return ukey ^ 0x80000000u;                               // unsigned cmp == signed cmp
}

// kA: coarse LDS histogram + ntri/mask outputs + flags (no global data atomics)
__global__ void kA_hist(const int* __restrict__ tets, const float* __restrict__ sdf,
                        unsigned* __restrict__ gHist, unsigned* __restrict__ flags,
                        float* __restrict__ out_ntri, float* __restrict__ out_mask) {
    __shared__ unsigned h[NC];
    __shared__ unsigned bf[2];
    int tid = threadIdx.x;
    for (int i = tid; i < NC; i += 256) h[i] = 0;
    if (tid == 0) { bf[0] = 0; bf[1] = 0; }
    __syncthreads();
    bool anyInv = false, anyZ = false;
    for (int f = blockIdx.x * 256 + tid; f < NFF; f += NBLK1 * 256) {
        const int4 tv = ((const int4*)tets)[f];
        int v0 = tv.x, v1 = tv.y, v2 = tv.z, v3 = tv.w;
        int ti = tidx(sdf, v0, v1, v2, v3);
        unsigned row = TROW[ti];
        bool has1 = (row & 7u) != 7u;
        bool has2 = ((row >> 9) & 7u) != 7u;
        out_ntri[f] = has2 ? 2.0f : (has1 ? 1.0f : 0.0f);
        ((float2*)out_mask)[f] = make_float2(has1 ? 1.0f : 0.0f, has2 ? 1.0f : 0.0f);
        if (!has1) { anyInv = true; continue; }
#define H_EDGE(A,B) { unsigned sk_ = skey_of(A, B); \
    if (sk_ == 0x80000000u) anyZ = true; \
    atomicAdd(&h[sk_ >> CSH], 1u); }
        H_EDGE(v0, v1) H_EDGE(v0, v2) H_EDGE(v0, v3)
        H_EDGE(v1, v2) H_EDGE(v1, v3) H_EDGE(v2, v3)
#undef H_EDGE
    }
    if (anyInv) atomicOr(&bf[0], 1u);
    if (anyZ) atomicOr(&bf[1], 1u);
    __syncthreads();
    for (int i = tid; i < NC; i += 256)
        gHist[(size_t)i * NBLK1 + blockIdx.x] = h[i];
    if (tid == 0) {
        if (bf[0]) atomicOr(&flags[0], 1u);
        if (bf[1]) atomicOr(&flags[1], 1u);
    }
}

// exclusive block scan (Hillis-Steele); bsums optional
__global__ void scan_block(const unsigned* __restrict__ in, unsigned* __restrict__ out,
                           unsigned* __restrict__ bsums, int n) {
    __shared__ unsigned s[1024];
    int tid = threadIdx.x;
    int g = blockIdx.x * 1024 + tid;
    unsigned v = (g < n) ? in[g] : 0u;
    s[tid] = v;
    __syncthreads();
    for (int off = 1; off < 1024; off <<= 1) {
        unsigned t = (tid >= off) ? s[tid - off] : 0u;
        __syncthreads();
        s[tid] += t;
        __syncthreads();
    }
    if (g < n) out[g] = s[tid] - v;  // exclusive
    if (tid == 1023 && bsums) bsums[blockIdx.x] = s[1023];
}

__global__ void scan_add(unsigned* __restrict__ out, const unsigned* __restrict__ ssums,
                         const unsigned* __restrict__ in, unsigned* __restrict__ total, int n) {
    int g = blockIdx.x * 1024 + threadIdx.x;
    if (g >= n) return;
    unsigned v = out[g] + ssums[g >> 10];
    out[g] = v;
    if (g == n - 1) *total = v + in[g];
}

// kB: scatter pairs into coarse-grouped staging via LDS cursors
__global__ void kB_scatter(const int* __restrict__ tets, const float* __restrict__ sdf,
                           const unsigned* __restrict__ gScan, uint2* __restrict__ staging) {
    __shared__ unsigned cur[NC];
    int tid = threadIdx.x;
    for (int i = tid; i < NC; i += 256)
        cur[i] = gScan[(size_t)i * NBLK1 + blockIdx.x];
    __syncthreads();
    for (int f = blockIdx.x * 256 + tid; f < NFF; f += NBLK1 * 256) {
        const int4 tv = ((const int4*)tets)[f];
        int v0 = tv.x, v1 = tv.y, v2 = tv.z, v3 = tv.w;
        int ti = tidx(sdf, v0, v1, v2, v3);
        if (ti == 0 || ti == 15) continue;
        unsigned base = (unsigned)f * 6u;
#define S_EDGE(A,B,E) { unsigned sk_ = skey_of(A, B); \
    unsigned p_ = atomicAdd(&cur[sk_ >> CSH], 1u); \
    staging[p_] = make_uint2(sk_, base + (E)); }
        S_EDGE(v0, v1, 0u) S_EDGE(v0, v2, 1u) S_EDGE(v0, v3, 2u)
        S_EDGE(v1, v2, 3u) S_EDGE(v1, v3, 4u) S_EDGE(v2, v3, 5u)
#undef S_EDGE
    }
}

// kC: per-coarse-bucket fine sort -> bPair + off1 (one block per coarse bucket)
__global__ void kC_fine(const unsigned* __restrict__ gScan, const unsigned* __restrict__ totalE,
                        const uint2* __restrict__ staging, uint2* __restrict__ bPair,
                        unsigned* __restrict__ off1) {
    __shared__ unsigned fh[NF2];
    __shared__ unsigned fs[NF2];
    int c = blockIdx.x, tid = threadIdx.x;
    unsigned s = gScan[(size_t)c * NBLK1];
    unsigned e = (c < NC - 1) ? gScan[(size_t)(c + 1) * NBLK1] : *totalE;
    for (int i = tid; i < NF2; i += 256) fh[i] = 0;
    __syncthreads();
    for (unsigned i = s + tid; i < e; i += 256)
        atomicAdd(&fh[(staging[i].x >> BSH) & (NF2 - 1)], 1u);
    __syncthreads();
    if (tid == 0) {
        unsigned acc = 0;
        for (int i = 0; i < NF2; i++) { fs[i] = acc; acc += fh[i]; }
    }
    __syncthreads();
    for (int i = tid; i < NF2; i += 256) {
        unsigned v = s + fs[i];
        off1[(size_t)c * NF2 + i] = v;
        fh[i] = v;                       // running cursor
    }
    __syncthreads();
    for (unsigned i = s + tid; i < e; i += 256) {
        uint2 t = staging[i];
        unsigned pos = atomicAdd(&fh[(t.x >> BSH) & (NF2 - 1)], 1u);
        bPair[pos] = t;
    }
}

// K2: wave-per-bucket distinct count via LDS
__global__ void k2_count(const unsigned* __restrict__ off1,
                         const uint2* __restrict__ bPair,
                         unsigned* __restrict__ dcnt) {
    __shared__ unsigned keys[4][BCAP];
    int w = threadIdx.x >> 6, lane = threadIdx.x & 63;
    unsigned b = blockIdx.x * 4u + (unsigned)w;
    unsigned s = off1[b], e = off1[b + 1];
    unsigned n = e - s;
    bool ok = (n <= BCAP);
    if (ok) for (unsigned i = lane; i < n; i += 64) keys[w][i] = bPair[s + i].x;
    __syncthreads();
    unsigned cnt = 0;
    if (ok) {
        for (unsigned i = lane; i < n; i += 64) {
            unsigned my = keys[w][i];
            bool rep = true;
            for (unsigned j = 0; j < i; j++)
                if (keys[w][j] == my) { rep = false; break; }
            cnt += rep ? 1u : 0u;
        }
    } else {
        for (unsigned i = lane; i < n; i += 64) {
            unsigned my = bPair[s + i].x;
            bool rep = true;
            for (unsigned j = 0; j < i; j++)
                if (bPair[s + j].x == my) { rep = false; break; }
            cnt += rep ? 1u : 0u;
        }
    }
#pragma unroll
    for (int o = 32; o > 0; o >>= 1) cnt += __shfl_down(cnt, o);
    if (lane == 0) dcnt[b] = cnt;
}

// decode wrapped int32 key -> gather indices (JAX floor-div + negative wrap)
__device__ __forceinline__ void decode_key(unsigned sk, int* iua, int* iub) {
    int key = (int)(sk ^ 0x80000000u);
    long long kk = (long long)key;
    long long q = kk / 300000LL;
    long long r = kk - q * 300000LL;
    if (r < 0) { q -= 1; r += 300000LL; }
    int ua = (int)q;
    if (ua < 0) ua += NVV;
    *iua = ua;
    *iub = (int)r;
}

__device__ __forceinline__ void write_vert(unsigned sk, unsigned g,
                                           const float* __restrict__ pos,
                                           const float* __restrict__ sdf,
                                           float* __restrict__ out_verts,
                                           float* __restrict__ out_cross) {
    int ua, ub;
    decode_key(sk, &ua, &ub);
    float s0 = sdf[ua], s1 = sdf[ub];
    bool cr = (s0 > 0.0f) != (s1 > 0.0f);
    out_cross[g] = cr ? 1.0f : 0.0f;
    if (cr) {
        float denom = s0 - s1;
        float wa = -s1 / denom, wb = s0 / denom;
        out_verts[g * 3 + 0] = wa * pos[ua * 3 + 0] + wb * pos[ub * 3 + 0];
        out_verts[g * 3 + 1] = wa * pos[ua * 3 + 1] + wb * pos[ub * 3 + 1];
        out_verts[g * 3 + 2] = wa * pos[ua * 3 + 2] + wb * pos[ub * 3 + 2];
    }
}

// K3: wave-per-bucket ranks via LDS -> idx_map; reps write verts/cross
__global__ void k3_rank(const float* __restrict__ pos, const float* __restrict__ sdf,
                        const unsigned* __restrict__ off1, const uint2* __restrict__ bPair,
                        const unsigned* __restrict__ base2, const unsigned* __restrict__ flags,
                        unsigned* __restrict__ idx_map,
                        float* __restrict__ out_verts, float* __restrict__ out_cross) {
    __shared__ unsigned keys[4][BCAP];
    __shared__ unsigned origs[4][BCAP];
    __shared__ unsigned char repf[4][BCAP];
    int w = threadIdx.x >> 6, lane = threadIdx.x & 63;
    unsigned b = blockIdx.x * 4u + (unsigned)w;
    unsigned s = off1[b], e = off1[b + 1];
    unsigned n = e - s;
    bool ok = (n <= BCAP);
    if (ok) for (unsigned i = lane; i < n; i += 64) {
        uint2 t = bPair[s + i];
        keys[w][i] = t.x;
        origs[w][i] = t.y;
    }
    __syncthreads();
    if (ok) for (unsigned i = lane; i < n; i += 64) {
        unsigned my = keys[w][i];
        unsigned char r = 1;
        for (unsigned j = 0; j < i; j++)
            if (keys[w][j] == my) { r = 0; break; }
        repf[w][i] = r;
    }
    __syncthreads();
    bool needZ = (flags[0] != 0u) && (flags[1] == 0u);
    unsigned bb = base2[b];
    if (ok) {
        for (unsigned i = lane; i < n; i += 64) {
            unsigned my = keys[w][i];
            unsigned rank = 0;
            for (unsigned j = 0; j < n; j++)
                rank += (repf[w][j] && keys[w][j] < my) ? 1u : 0u;
            unsigned g = bb + rank + ((needZ && my > 0x80000000u) ? 1u : 0u);
            idx_map[origs[w][i]] = g;
            if (repf[w][i]) write_vert(my, g, pos, sdf, out_verts, out_cross);
        }
    } else {
        for (unsigned i = lane; i < n; i += 64) {
            unsigned my = bPair[s + i].x;
            bool isrep = true;
            for (unsigned j = 0; j < i; j++)
                if (bPair[s + j].x == my) { isrep = false; break; }
            unsigned rank = 0;
            for (unsigned j = 0; j < n; j++) {
                unsigned kj = bPair[s + j].x;
                if (kj < my) {
                    bool jr = true;
                    for (unsigned k = 0; k < j; k++)
                        if (bPair[s + k].x == kj) { jr = false; break; }
                    rank += jr ? 1u : 0u;
                }
            }
            unsigned g = bb + rank + ((needZ && my > 0x80000000u) ? 1u : 0u);
            idx_map[bPair[s + i].y] = g;
            if (isrep) write_vert(my, g, pos, sdf, out_verts, out_cross);
        }
    }
}

// K5: faces — coalesced gather from idx_map (u32, same buffer), overwrite as float
__global__ void k5_faces(const int* __restrict__ tets, const float* __restrict__ sdf,
                         void* faces_buf) {
    int f = blockIdx.x * 256 + threadIdx.x;
    if (f >= NFF) return;
    const int4 tv = ((const int4*)tets)[f];
    int v0 = tv.x, v1 = tv.y, v2 = tv.z, v3 = tv.w;
    int ti = tidx(sdf, v0, v1, v2, v3);
    unsigned row = TROW[ti];
    bool has1 = (row & 7u) != 7u;
    bool has2 = ((row >> 9) & 7u) != 7u;
    float* of = (float*)faces_buf + (size_t)f * 6;
    if (!has1) {
        of[0] = -1.0f; of[1] = -1.0f; of[2] = -1.0f;
        of[3] = -1.0f; of[4] = -1.0f; of[5] = -1.0f;
        return;
    }
    const unsigned* im = (const unsigned*)faces_buf + (size_t)f * 6;
    float g0 = (float)im[0], g1 = (float)im[1], g2 = (float)im[2];
    float g3 = (float)im[3], g4 = (float)im[4], g5 = (float)im[5];
    unsigned l0 = row & 7u,         l1 = (row >> 3) & 7u,  l2 = (row >> 6) & 7u;
    unsigned l3 = (row >> 9) & 7u,  l4 = (row >> 12) & 7u, l5 = (row >> 15) & 7u;
#define SEL(L) ((L) == 0u ? g0 : (L) == 1u ? g1 : (L) == 2u ? g2 : \
                (L) == 3u ? g3 : (L) == 4u ? g4 : g5)
    float o0 = SEL(l0), o1 = SEL(l1), o2 = SEL(l2);
    float o3 = has2 ? SEL(l3) : -1.0f;
    float o4 = has2 ? SEL(l4) : -1.0f;
    float o5 = has2 ? SEL(l5) : -1.0f;
#undef SEL
    of[0] = o0; of[1] = o1; of[2] = o2;
    of[3] = o3; of[4] = o4; of[5] = o5;
}

// K6: uv atlas — runs LAST over the uvs region
__global__ void k6_uvs(float* __restrict__ out_uvs) {
    int c = blockIdx.x * 256 + threadIdx.x;
    if (c >= NGRID * NGRID) return;
    int i = c / NGRID, j = c - i * NGRID;
    const float inv = 1.0f / (float)NGRID;
    const float pad = 0.9f / (float)NGRID;
    float x = (float)j * inv;
    float y = (float)i * inv;
    float4* o = (float4*)(out_uvs + (size_t)c * 8);
    o[0] = make_float4(x, y, x + pad, y);
    o[1] = make_float4(x + pad, y + pad, x, y + pad);
}

// K7: uv_idx — runs LAST over the uv_idx region
__global__ void k7_uvidx(float* __restrict__ out_uvidx) {
    int f = blockIdx.x * 256 + threadIdx.x;
    if (f >= NFF) return;
    float base = (float)(4 * f);
    float2* uvi = (float2*)(out_uvidx + (size_t)f * 6);
    uvi[0] = make_float2(base, base + 1.0f);
    uvi[1] = make_float2(base + 2.0f, base);
    uvi[2] = make_float2(base + 2.0f, base + 3.0f);
}

extern "C" void kernel_launch(void* const* d_in, const int* in_sizes, int n_in,
                              void* d_out, int out_size, void* d_ws, size_t ws_size,
                              hipStream_t stream) {
    const float* pos = (const float*)d_in[0];
    const float* sdf = (const float*)d_in[1];
    const int* tets = (const int*)d_in[2];
    float* out = (float*)d_out;
    unsigned* u = (unsigned*)d_out;

    uint2*    bPair   = (uint2*)(u + S_PAIR);
    unsigned* gHist   = u + S_GH;
    unsigned* gScan   = u + S_GS;
    unsigned* dcnt    = u + S_DCNT;
    unsigned* off1    = u + S_OFF1;
    unsigned* base2   = u + S_BASE2;
    unsigned* bsums   = u + S_BSUMS;
    unsigned* ssums   = u + S_SSUMS;
    unsigned* flags   = u + S_FLG;
    unsigned* idx_map = u + OFF_FACES;
    uint2*    staging = (uint2*)(u + OFF_VERTS);   // verts region until kC done

    // flags + cross region zeroed up front (disjoint from staging)
    hipMemsetAsync(flags, 0, 8 * 4, stream);
    hipMemsetAsync(out + OFF_CROSS, 0, (size_t)9000000 * 4, stream);

    dim3 blk(256);
    int gF = (NFF + 255) / 256;
    int gB = NB / 4;

    kA_hist<<<NBLK1, blk, 0, stream>>>(tets, sdf, gHist, flags,
                                       out + OFF_NTRI, out + OFF_MASK);

    // scan1: gHist -> gScan (bin-major), total E -> off1[NB]
    scan_block<<<NHIST / 1024, 1024, 0, stream>>>(gHist, gScan, bsums, NHIST);
    scan_block<<<1, 1024, 0, stream>>>(bsums, ssums, nullptr, NHIST / 1024);
    scan_add<<<NHIST / 1024, 1024, 0, stream>>>(gScan, ssums, gHist, off1 + NB, NHIST);

    kB_scatter<<<NBLK1, blk, 0, stream>>>(tets, sdf, gScan, staging);
    kC_fine<<<NC, blk, 0, stream>>>(gScan, off1 + NB, staging, bPair, off1);

    // staging consumed -> verts region becomes the real (zeroed) verts output
    hipMemsetAsync(out + OFF_VERTS, 0, (size_t)27000000 * 4, stream);

    k2_count<<<gB, blk, 0, stream>>>(off1, bPair, dcnt);

    // scan2: dcnt -> base2 (+ total unused slot base2[NB])
    scan_block<<<NB / 1024, 1024, 0, stream>>>(dcnt, base2, bsums, NB);
    scan_block<<<1, 1024, 0, stream>>>(bsums, ssums, nullptr, NB / 1024);
    scan_add<<<NB / 1024, 1024, 0, stream>>>(base2, ssums, dcnt, base2 + NB, NB);

    k3_rank<<<gB, blk, 0, stream>>>(pos, sdf, off1, bPair, base2, flags,
                                    idx_map, out + OFF_VERTS, out + OFF_CROSS);
    k5_faces<<<gF, blk, 0, stream>>>(tets, sdf, (void*)(out + OFF_FACES));

    int gC = (NGRID * NGRID + 255) / 256;
    k6_uvs<<<gC, blk, 0, stream>>>(out + OFF_UVS);
    k7_uvidx<<<gF, blk, 0, stream>>>(out + OFF_UVIDX);
}

// Round 11
// 675.775 us; speedup vs baseline: 13.1148x; 1.1501x over previous
//
#include <hip/hip_runtime.h>
#include <stdint.h>

#define NVV 300000
#define NFF 1500000
#define NE  9000000
#define NGRID 1225
#define NB   262144        // key-space buckets = 2^18 (fine)
#define BSH  14            // fine bucket = skey >> BSH
#define BCAP 256           // LDS bucket capacity per wave (k2/k3 fallback)
#define NC   512           // coarse bins
#define CSH  23            // coarse bin = skey >> CSH
#define NF2  512           // fine bins per coarse
#define NBLK1 2048         // blocks for kA/kB
#define NHIST (NC * NBLK1) // 1,048,576

// d_out layout (float32 element offsets)
#define OFF_VERTS 0
#define OFF_FACES 27000000
#define OFF_MASK  36000000
#define OFF_NTRI  39000000
#define OFF_CROSS 40500000
#define OFF_UVS   49500000
#define OFF_UVIDX 61505000

// ALL scratch lives in d_out; d_ws never used.
#define S_PAIR  49500000u                  // bPair: 9M uint2 = 18M u32 -> 67.5M
#define S_GH    67500000u                  // gHist: 1,048,576
#define S_GS    (S_GH + NHIST)             // gScan: 1,048,576
#define S_DCNT  (S_GS + NHIST)             // NB
#define S_OFF1  (S_DCNT + NB)              // NB+1
#define S_BASE2 (S_OFF1 + NB + 1)          // NB+1
#define S_BSUMS (S_BASE2 + NB + 1)         // 1024
#define S_SSUMS (S_BSUMS + 1024)           // 1024
#define S_FLG   (S_SSUMS + 1024)           // 8 -> ends < 70,505,000
// staging: 9M uint2 in the verts region (memset after kC)
// idx_map: 9M u32 in the faces region (k3 -> k5)

#define ENC3(x) ((unsigned)(((x) < 0) ? 7 : (x)))
#define PACK6(a,b,c,d,e,f) (ENC3(a) | (ENC3(b)<<3) | (ENC3(c)<<6) | \
                            (ENC3(d)<<9) | (ENC3(e)<<12) | (ENC3(f)<<15))
__constant__ unsigned TROW[16] = {
    PACK6(-1,-1,-1,-1,-1,-1), PACK6(1,0,2,-1,-1,-1), PACK6(4,0,3,-1,-1,-1), PACK6(1,4,2,1,3,4),
    PACK6(3,1,5,-1,-1,-1),    PACK6(2,3,0,2,5,3),    PACK6(1,4,0,1,5,4),    PACK6(4,2,5,-1,-1,-1),
    PACK6(4,5,2,-1,-1,-1),    PACK6(4,1,0,4,5,1),    PACK6(3,2,0,3,5,2),    PACK6(1,3,5,-1,-1,-1),
    PACK6(4,1,2,4,3,1),       PACK6(3,0,4,-1,-1,-1), PACK6(2,0,1,-1,-1,-1), PACK6(-1,-1,-1,-1,-1,-1)};

__device__ __forceinline__ int tidx(const float* sdf, int v0, int v1, int v2, int v3) {
    int ti = 0;
    if (sdf[v0] > 0.0f) ti |= 1;
    if (sdf[v1] > 0.0f) ti |= 2;
    if (sdf[v2] > 0.0f) ti |= 4;
    if (sdf[v3] > 0.0f) ti |= 8;
    return ti;
}

__device__ __forceinline__ unsigned skey_of(int a, int b) {
    int ea = a < b ? a : b;
    int eb = a < b ? b : a;
    unsigned ukey = (unsigned)ea * 300000u + (unsigned)eb;   // wraps like int32
    return ukey ^ 0x80000000u;
}

// full-wave bitonic sort of (key, org), ascending, lexicographic tie-break.
// pads (0xFFFFFFFF, 0xFFFFFFFF) sort strictly last (real org < 2^31).
__device__ __forceinline__ void bitonic64(unsigned& key, unsigned& org, int lane) {
#pragma unroll
    for (int k = 2; k <= 64; k <<= 1) {
#pragma unroll
        for (int j = k >> 1; j > 0; j >>= 1) {
            unsigned pk = __shfl_xor(key, j, 64);
            unsigned po = __shfl_xor(org, j, 64);
            bool takeMin = (((lane & j) == 0) == ((lane & k) == 0));
            bool pLess  = (pk < key) || (pk == key && po < org);
            bool pGreat = (key < pk) || (pk == key && org < po);
            bool take = takeMin ? pLess : pGreat;
            if (take) { key = pk; org = po; }
        }
    }
}

// kA: coarse LDS histogram + ntri/mask outputs + flags
__global__ void kA_hist(const int* __restrict__ tets, const float* __restrict__ sdf,
                        unsigned* __restrict__ gHist, unsigned* __restrict__ flags,
                        float* __restrict__ out_ntri, float* __restrict__ out_mask) {
    __shared__ unsigned h[NC];
    __shared__ unsigned bf[2];
    int tid = threadIdx.x;
    for (int i = tid; i < NC; i += 256) h[i] = 0;
    if (tid == 0) { bf[0] = 0; bf[1] = 0; }
    __syncthreads();
    bool anyInv = false, anyZ = false;
    for (int f = blockIdx.x * 256 + tid; f < NFF; f += NBLK1 * 256) {
        const int4 tv = ((const int4*)tets)[f];
        int v0 = tv.x, v1 = tv.y, v2 = tv.z, v3 = tv.w;
        int ti = tidx(sdf, v0, v1, v2, v3);
        unsigned row = TROW[ti];
        bool has1 = (row & 7u) != 7u;
        bool has2 = ((row >> 9) & 7u) != 7u;
        out_ntri[f] = has2 ? 2.0f : (has1 ? 1.0f : 0.0f);
        ((float2*)out_mask)[f] = make_float2(has1 ? 1.0f : 0.0f, has2 ? 1.0f : 0.0f);
        if (!has1) { anyInv = true; continue; }
#define H_EDGE(A,B) { unsigned sk_ = skey_of(A, B); \
    if (sk_ == 0x80000000u) anyZ = true; \
    atomicAdd(&h[sk_ >> CSH], 1u); }
        H_EDGE(v0, v1) H_EDGE(v0, v2) H_EDGE(v0, v3)
        H_EDGE(v1, v2) H_EDGE(v1, v3) H_EDGE(v2, v3)
#undef H_EDGE
    }
    if (anyInv) atomicOr(&bf[0], 1u);
    if (anyZ) atomicOr(&bf[1], 1u);
    __syncthreads();
    for (int i = tid; i < NC; i += 256)
        gHist[(size_t)i * NBLK1 + blockIdx.x] = h[i];
    if (tid == 0) {
        if (bf[0]) atomicOr(&flags[0], 1u);
        if (bf[1]) atomicOr(&flags[1], 1u);
    }
}

// exclusive block scan (Hillis-Steele); bsums optional
__global__ void scan_block(const unsigned* __restrict__ in, unsigned* __restrict__ out,
                           unsigned* __restrict__ bsums, int n) {
    __shared__ unsigned s[1024];
    int tid = threadIdx.x;
    int g = blockIdx.x * 1024 + tid;
    unsigned v = (g < n) ? in[g] : 0u;
    s[tid] = v;
    __syncthreads();
    for (int off = 1; off < 1024; off <<= 1) {
        unsigned t = (tid >= off) ? s[tid - off] : 0u;
        __syncthreads();
        s[tid] += t;
        __syncthreads();
    }
    if (g < n) out[g] = s[tid] - v;
    if (tid == 1023 && bsums) bsums[blockIdx.x] = s[1023];
}

__global__ void scan_add(unsigned* __restrict__ out, const unsigned* __restrict__ ssums,
                         const unsigned* __restrict__ in, unsigned* __restrict__ total, int n) {
    int g = blockIdx.x * 1024 + threadIdx.x;
    if (g >= n) return;
    unsigned v = out[g] + ssums[g >> 10];
    out[g] = v;
    if (g == n - 1) *total = v + in[g];
}

// kB: scatter pairs into coarse-grouped staging via LDS cursors
__global__ void kB_scatter(const int* __restrict__ tets, const float* __restrict__ sdf,
                           const unsigned* __restrict__ gScan, uint2* __restrict__ staging) {
    __shared__ unsigned cur[NC];
    int tid = threadIdx.x;
    for (int i = tid; i < NC; i += 256)
        cur[i] = gScan[(size_t)i * NBLK1 + blockIdx.x];
    __syncthreads();
    for (int f = blockIdx.x * 256 + tid; f < NFF; f += NBLK1 * 256) {
        const int4 tv = ((const int4*)tets)[f];
        int v0 = tv.x, v1 = tv.y, v2 = tv.z, v3 = tv.w;
        int ti = tidx(sdf, v0, v1, v2, v3);
        if (ti == 0 || ti == 15) continue;
        unsigned base = (unsigned)f * 6u;
#define S_EDGE(A,B,E) { unsigned sk_ = skey_of(A, B); \
    unsigned p_ = atomicAdd(&cur[sk_ >> CSH], 1u); \
    staging[p_] = make_uint2(sk_, base + (E)); }
        S_EDGE(v0, v1, 0u) S_EDGE(v0, v2, 1u) S_EDGE(v0, v3, 2u)
        S_EDGE(v1, v2, 3u) S_EDGE(v1, v3, 4u) S_EDGE(v2, v3, 5u)
#undef S_EDGE
    }
}

// kC: per-coarse-bucket fine binning -> bPair + off1
__global__ void kC_fine(const unsigned* __restrict__ gScan, const unsigned* __restrict__ totalE,
                        const uint2* __restrict__ staging, uint2* __restrict__ bPair,
                        unsigned* __restrict__ off1) {
    __shared__ unsigned fh[NF2];
    __shared__ unsigned fs[NF2];
    int c = blockIdx.x, tid = threadIdx.x;
    unsigned s = gScan[(size_t)c * NBLK1];
    unsigned e = (c < NC - 1) ? gScan[(size_t)(c + 1) * NBLK1] : *totalE;
    for (int i = tid; i < NF2; i += 256) fh[i] = 0;
    __syncthreads();
    for (unsigned i = s + tid; i < e; i += 256)
        atomicAdd(&fh[(staging[i].x >> BSH) & (NF2 - 1)], 1u);
    __syncthreads();
    if (tid == 0) {
        unsigned acc = 0;
        for (int i = 0; i < NF2; i++) { fs[i] = acc; acc += fh[i]; }
    }
    __syncthreads();
    for (int i = tid; i < NF2; i += 256) {
        unsigned v = s + fs[i];
        off1[(size_t)c * NF2 + i] = v;
        fh[i] = v;
    }
    __syncthreads();
    for (unsigned i = s + tid; i < e; i += 256) {
        uint2 t = staging[i];
        unsigned pos = atomicAdd(&fh[(t.x >> BSH) & (NF2 - 1)], 1u);
        bPair[pos] = t;
    }
}

// K2: wave-per-bucket distinct count — register bitonic fast path
__global__ void k2_count(const unsigned* __restrict__ off1,
                         const uint2* __restrict__ bPair,
                         unsigned* __restrict__ dcnt) {
    __shared__ unsigned keys[4][BCAP];
    int w = threadIdx.x >> 6, lane = threadIdx.x & 63;
    unsigned b = blockIdx.x * 4u + (unsigned)w;
    unsigned s = off1[b], e = off1[b + 1];
    unsigned n = e - s;
    bool fast = (n <= 64u);
    bool lds = !fast && (n <= BCAP);
    if (lds) for (unsigned i = lane; i < n; i += 64) keys[w][i] = bPair[s + i].x;
    __syncthreads();
    if (fast) {
        unsigned key = 0xFFFFFFFFu, org = 0xFFFFFFFFu;
        if (lane < (int)n) { uint2 t = bPair[s + lane]; key = t.x; org = t.y; }
        bitonic64(key, org, lane);
        bool valid = (org != 0xFFFFFFFFu);
        unsigned prev = __shfl_up(key, 1, 64);
        bool rep = valid && (lane == 0 || key != prev);
        unsigned long long m = __ballot(rep);
        if (lane == 0) dcnt[b] = (unsigned)__popcll(m);
        return;
    }
    unsigned cnt = 0;
    if (lds) {
        for (unsigned i = lane; i < n; i += 64) {
            unsigned my = keys[w][i];
            bool rep = true;
            for (unsigned j = 0; j < i; j++)
                if (keys[w][j] == my) { rep = false; break; }
            cnt += rep ? 1u : 0u;
        }
    } else {
        for (unsigned i = lane; i < n; i += 64) {
            unsigned my = bPair[s + i].x;
            bool rep = true;
            for (unsigned j = 0; j < i; j++)
                if (bPair[s + j].x == my) { rep = false; break; }
            cnt += rep ? 1u : 0u;
        }
    }
#pragma unroll
    for (int o = 32; o > 0; o >>= 1) cnt += __shfl_down(cnt, o);
    if (lane == 0) dcnt[b] = cnt;
}

__device__ __forceinline__ void decode_key(unsigned sk, int* iua, int* iub) {
    int key = (int)(sk ^ 0x80000000u);
    long long kk = (long long)key;
    long long q = kk / 300000LL;
    long long r = kk - q * 300000LL;
    if (r < 0) { q -= 1; r += 300000LL; }
    int ua = (int)q;
    if (ua < 0) ua += NVV;
    *iua = ua;
    *iub = (int)r;
}

__device__ __forceinline__ void write_vert(unsigned sk, unsigned g,
                                           const float* __restrict__ pos,
                                           const float* __restrict__ sdf,
                                           float* __restrict__ out_verts,
                                           float* __restrict__ out_cross) {
    int ua, ub;
    decode_key(sk, &ua, &ub);
    float s0 = sdf[ua], s1 = sdf[ub];
    bool cr = (s0 > 0.0f) != (s1 > 0.0f);
    out_cross[g] = cr ? 1.0f : 0.0f;
    if (cr) {
        float denom = s0 - s1;
        float wa = -s1 / denom, wb = s0 / denom;
        out_verts[g * 3 + 0] = wa * pos[ua * 3 + 0] + wb * pos[ub * 3 + 0];
        out_verts[g * 3 + 1] = wa * pos[ua * 3 + 1] + wb * pos[ub * 3 + 1];
        out_verts[g * 3 + 2] = wa * pos[ua * 3 + 2] + wb * pos[ub * 3 + 2];
    }
}

// K3: wave-per-bucket ranks — register bitonic fast path
__global__ void k3_rank(const float* __restrict__ pos, const float* __restrict__ sdf,
                        const unsigned* __restrict__ off1, const uint2* __restrict__ bPair,
                        const unsigned* __restrict__ base2, const unsigned* __restrict__ flags,
                        unsigned* __restrict__ idx_map,
                        float* __restrict__ out_verts, float* __restrict__ out_cross) {
    __shared__ unsigned keys[4][BCAP];
    __shared__ unsigned origs[4][BCAP];
    __shared__ unsigned char repf[4][BCAP];
    int w = threadIdx.x >> 6, lane = threadIdx.x & 63;
    unsigned b = blockIdx.x * 4u + (unsigned)w;
    unsigned s = off1[b], e = off1[b + 1];
    unsigned n = e - s;
    bool fast = (n <= 64u);
    bool lds = !fast && (n <= BCAP);
    bool needZ = (flags[0] != 0u) && (flags[1] == 0u);
    unsigned bb = base2[b];
    if (lds) for (unsigned i = lane; i < n; i += 64) {
        uint2 t = bPair[s + i];
        keys[w][i] = t.x;
        origs[w][i] = t.y;
    }
    __syncthreads();
    if (lds) for (unsigned i = lane; i < n; i += 64) {
        unsigned my = keys[w][i];
        unsigned char r = 1;
        for (unsigned j = 0; j < i; j++)
            if (keys[w][j] == my) { r = 0; break; }
        repf[w][i] = r;
    }
    __syncthreads();
    if (fast) {
        unsigned key = 0xFFFFFFFFu, org = 0xFFFFFFFFu;
        if (lane < (int)n) { uint2 t = bPair[s + lane]; key = t.x; org = t.y; }
        bitonic64(key, org, lane);
        bool valid = (org != 0xFFFFFFFFu);
        unsigned prev = __shfl_up(key, 1, 64);
        bool rep = valid && (lane == 0 || key != prev);
        unsigned long long m = __ballot(rep);
        unsigned rank = (unsigned)__popcll(m & ((1ull << lane) - 1ull));
        unsigned g = bb + rank + ((needZ && key > 0x80000000u) ? 1u : 0u);
        if (valid) idx_map[org] = g;
        if (rep) write_vert(key, g, pos, sdf, out_verts, out_cross);
        return;
    }
    if (lds) {
        for (unsigned i = lane; i < n; i += 64) {
            unsigned my = keys[w][i];
            unsigned rank = 0;
            for (unsigned j = 0; j < n; j++)
                rank += (repf[w][j] && keys[w][j] < my) ? 1u : 0u;
            unsigned g = bb + rank + ((needZ && my > 0x80000000u) ? 1u : 0u);
            idx_map[origs[w][i]] = g;
            if (repf[w][i]) write_vert(my, g, pos, sdf, out_verts, out_cross);
        }
    } else {
        for (unsigned i = lane; i < n; i += 64) {
            unsigned my = bPair[s + i].x;
            bool isrep = true;
            for (unsigned j = 0; j < i; j++)
                if (bPair[s + j].x == my) { isrep = false; break; }
            unsigned rank = 0;
            for (unsigned j = 0; j < n; j++) {
                unsigned kj = bPair[s + j].x;
                if (kj < my) {
                    bool jr = true;
                    for (unsigned k = 0; k < j; k++)
                        if (bPair[s + k].x == kj) { jr = false; break; }
                    rank += jr ? 1u : 0u;
                }
            }
            unsigned g = bb + rank + ((needZ && my > 0x80000000u) ? 1u : 0u);
            idx_map[bPair[s + i].y] = g;
            if (isrep) write_vert(my, g, pos, sdf, out_verts, out_cross);
        }
    }
}

// K5: faces — coalesced gather from idx_map (u32, same buffer), overwrite as float
__global__ void k5_faces(const int* __restrict__ tets, const float* __restrict__ sdf,
                         void* faces_buf) {
    int f = blockIdx.x * 256 + threadIdx.x;
    if (f >= NFF) return;
    const int4 tv = ((const int4*)tets)[f];
    int v0 = tv.x, v1 = tv.y, v2 = tv.z, v3 = tv.w;
    int ti = tidx(sdf, v0, v1, v2, v3);
    unsigned row = TROW[ti];
    bool has1 = (row & 7u) != 7u;
    bool has2 = ((row >> 9) & 7u) != 7u;
    float* of = (float*)faces_buf + (size_t)f * 6;
    if (!has1) {
        of[0] = -1.0f; of[1] = -1.0f; of[2] = -1.0f;
        of[3] = -1.0f; of[4] = -1.0f; of[5] = -1.0f;
        return;
    }
    const unsigned* im = (const unsigned*)faces_buf + (size_t)f * 6;
    float g0 = (float)im[0], g1 = (float)im[1], g2 = (float)im[2];
    float g3 = (float)im[3], g4 = (float)im[4], g5 = (float)im[5];
    unsigned l0 = row & 7u,         l1 = (row >> 3) & 7u,  l2 = (row >> 6) & 7u;
    unsigned l3 = (row >> 9) & 7u,  l4 = (row >> 12) & 7u, l5 = (row >> 15) & 7u;
#define SEL(L) ((L) == 0u ? g0 : (L) == 1u ? g1 : (L) == 2u ? g2 : \
                (L) == 3u ? g3 : (L) == 4u ? g4 : g5)
    float o0 = SEL(l0), o1 = SEL(l1), o2 = SEL(l2);
    float o3 = has2 ? SEL(l3) : -1.0f;
    float o4 = has2 ? SEL(l4) : -1.0f;
    float o5 = has2 ? SEL(l5) : -1.0f;
#undef SEL
    of[0] = o0; of[1] = o1; of[2] = o2;
    of[3] = o3; of[4] = o4; of[5] = o5;
}

// K6: uv atlas — runs LAST over the uvs region
__global__ void k6_uvs(float* __restrict__ out_uvs) {
    int c = blockIdx.x * 256 + threadIdx.x;
    if (c >= NGRID * NGRID) return;
    int i = c / NGRID, j = c - i * NGRID;
    const float inv = 1.0f / (float)NGRID;
    const float pad = 0.9f / (float)NGRID;
    float x = (float)j * inv;
    float y = (float)i * inv;
    float4* o = (float4*)(out_uvs + (size_t)c * 8);
    o[0] = make_float4(x, y, x + pad, y);
    o[1] = make_float4(x + pad, y + pad, x, y + pad);
}

// K7: uv_idx — runs LAST over the uv_idx region
__global__ void k7_uvidx(float* __restrict__ out_uvidx) {
    int f = blockIdx.x * 256 + threadIdx.x;
    if (f >= NFF) return;
    float base = (float)(4 * f);
    float2* uvi = (float2*)(out_uvidx + (size_t)f * 6);
    uvi[0] = make_float2(base, base + 1.0f);
    uvi[1] = make_float2(base + 2.0f, base);
    uvi[2] = make_float2(base + 2.0f, base + 3.0f);
}

extern "C" void kernel_launch(void* const* d_in, const int* in_sizes, int n_in,
                              void* d_out, int out_size, void* d_ws, size_t ws_size,
                              hipStream_t stream) {
    const float* pos = (const float*)d_in[0];
    const float* sdf = (const float*)d_in[1];
    const int* tets = (const int*)d_in[2];
    float* out = (float*)d_out;
    unsigned* u = (unsigned*)d_out;

    uint2*    bPair   = (uint2*)(u + S_PAIR);
    unsigned* gHist   = u + S_GH;
    unsigned* gScan   = u + S_GS;
    unsigned* dcnt    = u + S_DCNT;
    unsigned* off1    = u + S_OFF1;
    unsigned* base2   = u + S_BASE2;
    unsigned* bsums   = u + S_BSUMS;
    unsigned* ssums   = u + S_SSUMS;
    unsigned* flags   = u + S_FLG;
    unsigned* idx_map = u + OFF_FACES;
    uint2*    staging = (uint2*)(u + OFF_VERTS);   // verts region until kC done

    hipMemsetAsync(flags, 0, 8 * 4, stream);
    hipMemsetAsync(out + OFF_CROSS, 0, (size_t)9000000 * 4, stream);

    dim3 blk(256);
    int gF = (NFF + 255) / 256;
    int gB = NB / 4;

    kA_hist<<<NBLK1, blk, 0, stream>>>(tets, sdf, gHist, flags,
                                       out + OFF_NTRI, out + OFF_MASK);

    scan_block<<<NHIST / 1024, 1024, 0, stream>>>(gHist, gScan, bsums, NHIST);
    scan_block<<<1, 1024, 0, stream>>>(bsums, ssums, nullptr, NHIST / 1024);
    scan_add<<<NHIST / 1024, 1024, 0, stream>>>(gScan, ssums, gHist, off1 + NB, NHIST);

    kB_scatter<<<NBLK1, blk, 0, stream>>>(tets, sdf, gScan, staging);
    kC_fine<<<NC, blk, 0, stream>>>(gScan, off1 + NB, staging, bPair, off1);

    hipMemsetAsync(out + OFF_VERTS, 0, (size_t)27000000 * 4, stream);

    k2_count<<<gB, blk, 0, stream>>>(off1, bPair, dcnt);

    scan_block<<<NB / 1024, 1024, 0, stream>>>(dcnt, base2, bsums, NB);
    scan_block<<<1, 1024, 0, stream>>>(bsums, ssums, nullptr, NB / 1024);
    scan_add<<<NB / 1024, 1024, 0, stream>>>(base2, ssums, dcnt, base2 + NB, NB);

    k3_rank<<<gB, blk, 0, stream>>>(pos, sdf, off1, bPair, base2, flags,
                                    idx_map, out + OFF_VERTS, out + OFF_CROSS);
    k5_faces<<<gF, blk, 0, stream>>>(tets, sdf, (void*)(out + OFF_FACES));

    int gC = (NGRID * NGRID + 255) / 256;
    k6_uvs<<<gC, blk, 0, stream>>>(out + OFF_UVS);
    k7_uvidx<<<gF, blk, 0, stream>>>(out + OFF_UVIDX);
}

// Round 12
// 643.413 us; speedup vs baseline: 13.7744x; 1.0503x over previous
//
#include <hip/hip_runtime.h>
#include <stdint.h>

#define NVV 300000
#define NFF 1500000
#define NE  9000000
#define NGRID 1225
#define NB   262144        // key-space buckets = 2^18 (fine)
#define BSH  14            // fine bucket = skey >> BSH
#define BCAP 256           // LDS bucket capacity per wave (k2/k3 fallback)
#define NC   512           // coarse bins
#define CSH  23            // coarse bin = skey >> CSH
#define NF2  512           // fine bins per coarse
#define NBLK1 2048         // blocks for kA/kB
#define NHIST (NC * NBLK1) // 1,048,576

// d_out layout (float32 element offsets)
#define OFF_VERTS 0
#define OFF_FACES 27000000
#define OFF_MASK  36000000
#define OFF_NTRI  39000000
#define OFF_CROSS 40500000
#define OFF_UVS   49500000
#define OFF_UVIDX 61505000

// ALL scratch lives in d_out; d_ws never used.
#define S_PAIR  49500000u                  // bPair: 9M uint2 = 18M u32 -> 67.5M
#define S_GH    67500000u                  // gHist: 1,048,576
#define S_GS    (S_GH + NHIST)             // gScan: 1,048,576
#define S_DCNT  (S_GS + NHIST)             // NB
#define S_OFF1  (S_DCNT + NB)              // NB+1
#define S_BASE2 (S_OFF1 + NB + 1)          // NB+1
#define S_BSUMS (S_BASE2 + NB + 1)         // 1024
#define S_SSUMS (S_BSUMS + 1024)           // 1024
#define S_FLG   (S_SSUMS + 1024)           // 8 -> ends < 70,505,000
// staging: 9M uint2 in the verts region (memset after kC)
// idx_map: 9M u32 in the faces region (k3 -> k5)

#define ENC3(x) ((unsigned)(((x) < 0) ? 7 : (x)))
#define PACK6(a,b,c,d,e,f) (ENC3(a) | (ENC3(b)<<3) | (ENC3(c)<<6) | \
                            (ENC3(d)<<9) | (ENC3(e)<<12) | (ENC3(f)<<15))
__constant__ unsigned TROW[16] = {
    PACK6(-1,-1,-1,-1,-1,-1), PACK6(1,0,2,-1,-1,-1), PACK6(4,0,3,-1,-1,-1), PACK6(1,4,2,1,3,4),
    PACK6(3,1,5,-1,-1,-1),    PACK6(2,3,0,2,5,3),    PACK6(1,4,0,1,5,4),    PACK6(4,2,5,-1,-1,-1),
    PACK6(4,5,2,-1,-1,-1),    PACK6(4,1,0,4,5,1),    PACK6(3,2,0,3,5,2),    PACK6(1,3,5,-1,-1,-1),
    PACK6(4,1,2,4,3,1),       PACK6(3,0,4,-1,-1,-1), PACK6(2,0,1,-1,-1,-1), PACK6(-1,-1,-1,-1,-1,-1)};

__device__ __forceinline__ int tidx(const float* sdf, int v0, int v1, int v2, int v3) {
    int ti = 0;
    if (sdf[v0] > 0.0f) ti |= 1;
    if (sdf[v1] > 0.0f) ti |= 2;
    if (sdf[v2] > 0.0f) ti |= 4;
    if (sdf[v3] > 0.0f) ti |= 8;
    return ti;
}

__device__ __forceinline__ unsigned skey_of(int a, int b) {
    int ea = a < b ? a : b;
    int eb = a < b ? b : a;
    unsigned ukey = (unsigned)ea * 300000u + (unsigned)eb;   // wraps like int32
    return ukey ^ 0x80000000u;
}

// full-wave bitonic sort of packed (key<<32 | org), ascending.
// pads 0xFFFFFFFF_FFFFFFFF sort strictly last (real org < 2^31).
__device__ __forceinline__ unsigned long long bitonic64p(unsigned long long v, int lane) {
    for (int k = 2; k <= 64; k <<= 1) {
        for (int j = k >> 1; j > 0; j >>= 1) {
            unsigned long long pv = __shfl_xor(v, j, 64);
            bool takeMin = (((lane & j) == 0) == ((lane & k) == 0));
            unsigned long long lo = pv < v ? pv : v;
            unsigned long long hi = pv < v ? v : pv;
            v = takeMin ? lo : hi;
        }
    }
    return v;
}

// kA: coarse LDS histogram + ntri/mask outputs + flags
__global__ void kA_hist(const int* __restrict__ tets, const float* __restrict__ sdf,
                        unsigned* __restrict__ gHist, unsigned* __restrict__ flags,
                        float* __restrict__ out_ntri, float* __restrict__ out_mask) {
    __shared__ unsigned h[NC];
    __shared__ unsigned bf[2];
    int tid = threadIdx.x;
    for (int i = tid; i < NC; i += 256) h[i] = 0;
    if (tid == 0) { bf[0] = 0; bf[1] = 0; }
    __syncthreads();
    bool anyInv = false, anyZ = false;
    for (int f = blockIdx.x * 256 + tid; f < NFF; f += NBLK1 * 256) {
        const int4 tv = ((const int4*)tets)[f];
        int v0 = tv.x, v1 = tv.y, v2 = tv.z, v3 = tv.w;
        int ti = tidx(sdf, v0, v1, v2, v3);
        unsigned row = TROW[ti];
        bool has1 = (row & 7u) != 7u;
        bool has2 = ((row >> 9) & 7u) != 7u;
        out_ntri[f] = has2 ? 2.0f : (has1 ? 1.0f : 0.0f);
        ((float2*)out_mask)[f] = make_float2(has1 ? 1.0f : 0.0f, has2 ? 1.0f : 0.0f);
        if (!has1) { anyInv = true; continue; }
#define H_EDGE(A,B) { unsigned sk_ = skey_of(A, B); \
    if (sk_ == 0x80000000u) anyZ = true; \
    atomicAdd(&h[sk_ >> CSH], 1u); }
        H_EDGE(v0, v1) H_EDGE(v0, v2) H_EDGE(v0, v3)
        H_EDGE(v1, v2) H_EDGE(v1, v3) H_EDGE(v2, v3)
#undef H_EDGE
    }
    if (anyInv) atomicOr(&bf[0], 1u);
    if (anyZ) atomicOr(&bf[1], 1u);
    __syncthreads();
    for (int i = tid; i < NC; i += 256)
        gHist[(size_t)i * NBLK1 + blockIdx.x] = h[i];
    if (tid == 0) {
        if (bf[0]) atomicOr(&flags[0], 1u);
        if (bf[1]) atomicOr(&flags[1], 1u);
    }
}

// exclusive block scan (Hillis-Steele); bsums optional
__global__ void scan_block(const unsigned* __restrict__ in, unsigned* __restrict__ out,
                           unsigned* __restrict__ bsums, int n) {
    __shared__ unsigned s[1024];
    int tid = threadIdx.x;
    int g = blockIdx.x * 1024 + tid;
    unsigned v = (g < n) ? in[g] : 0u;
    s[tid] = v;
    __syncthreads();
    for (int off = 1; off < 1024; off <<= 1) {
        unsigned t = (tid >= off) ? s[tid - off] : 0u;
        __syncthreads();
        s[tid] += t;
        __syncthreads();
    }
    if (g < n) out[g] = s[tid] - v;
    if (tid == 1023 && bsums) bsums[blockIdx.x] = s[1023];
}

__global__ void scan_add(unsigned* __restrict__ out, const unsigned* __restrict__ ssums,
                         const unsigned* __restrict__ in, unsigned* __restrict__ total, int n) {
    int g = blockIdx.x * 1024 + threadIdx.x;
    if (g >= n) return;
    unsigned v = out[g] + ssums[g >> 10];
    out[g] = v;
    if (g == n - 1) *total = v + in[g];
}

// kB: scatter pairs into coarse-grouped staging via LDS cursors
__global__ void kB_scatter(const int* __restrict__ tets, const float* __restrict__ sdf,
                           const unsigned* __restrict__ gScan, uint2* __restrict__ staging) {
    __shared__ unsigned cur[NC];
    int tid = threadIdx.x;
    for (int i = tid; i < NC; i += 256)
        cur[i] = gScan[(size_t)i * NBLK1 + blockIdx.x];
    __syncthreads();
    for (int f = blockIdx.x * 256 + tid; f < NFF; f += NBLK1 * 256) {
        const int4 tv = ((const int4*)tets)[f];
        int v0 = tv.x, v1 = tv.y, v2 = tv.z, v3 = tv.w;
        int ti = tidx(sdf, v0, v1, v2, v3);
        if (ti == 0 || ti == 15) continue;
        unsigned base = (unsigned)f * 6u;
#define S_EDGE(A,B,E) { unsigned sk_ = skey_of(A, B); \
    unsigned p_ = atomicAdd(&cur[sk_ >> CSH], 1u); \
    staging[p_] = make_uint2(sk_, base + (E)); }
        S_EDGE(v0, v1, 0u) S_EDGE(v0, v2, 1u) S_EDGE(v0, v3, 2u)
        S_EDGE(v1, v2, 3u) S_EDGE(v1, v3, 4u) S_EDGE(v2, v3, 5u)
#undef S_EDGE
    }
}

// kC: per-coarse-bucket fine binning -> bPair + off1
__global__ void kC_fine(const unsigned* __restrict__ gScan, const unsigned* __restrict__ totalE,
                        const uint2* __restrict__ staging, uint2* __restrict__ bPair,
                        unsigned* __restrict__ off1) {
    __shared__ unsigned fh[NF2];
    __shared__ unsigned fs[NF2];
    int c = blockIdx.x, tid = threadIdx.x;
    unsigned s = gScan[(size_t)c * NBLK1];
    unsigned e = (c < NC - 1) ? gScan[(size_t)(c + 1) * NBLK1] : *totalE;
    for (int i = tid; i < NF2; i += 256) fh[i] = 0;
    __syncthreads();
    for (unsigned i = s + tid; i < e; i += 256)
        atomicAdd(&fh[(staging[i].x >> BSH) & (NF2 - 1)], 1u);
    __syncthreads();
    if (tid == 0) {
        unsigned acc = 0;
        for (int i = 0; i < NF2; i++) { fs[i] = acc; acc += fh[i]; }
    }
    __syncthreads();
    for (int i = tid; i < NF2; i += 256) {
        unsigned v = s + fs[i];
        off1[(size_t)c * NF2 + i] = v;
        fh[i] = v;
    }
    __syncthreads();
    for (unsigned i = s + tid; i < e; i += 256) {
        uint2 t = staging[i];
        unsigned pos = atomicAdd(&fh[(t.x >> BSH) & (NF2 - 1)], 1u);
        bPair[pos] = t;
    }
}

// K2: wave-per-bucket distinct count — packed register bitonic fast path
__global__ void k2_count(const unsigned* __restrict__ off1,
                         const uint2* __restrict__ bPair,
                         unsigned* __restrict__ dcnt) {
    __shared__ unsigned keys[4][BCAP];
    int w = threadIdx.x >> 6, lane = threadIdx.x & 63;
    unsigned b = blockIdx.x * 4u + (unsigned)w;
    unsigned s = off1[b], e = off1[b + 1];
    unsigned n = e - s;
    bool fast = (n <= 64u);
    bool lds = !fast && (n <= BCAP);
    if (lds) for (unsigned i = lane; i < n; i += 64) keys[w][i] = bPair[s + i].x;
    __syncthreads();
    if (fast) {
        unsigned long long v = 0xFFFFFFFFFFFFFFFFull;
        if (lane < (int)n) {
            uint2 t = bPair[s + lane];
            v = ((unsigned long long)t.x << 32) | t.y;
        }
        v = bitonic64p(v, lane);
        unsigned key = (unsigned)(v >> 32);
        bool valid = (v != 0xFFFFFFFFFFFFFFFFull);
        unsigned prev = __shfl_up(key, 1, 64);
        bool rep = valid && (lane == 0 || key != prev);
        unsigned long long m = __ballot(rep);
        if (lane == 0) dcnt[b] = (unsigned)__popcll(m);
        return;
    }
    unsigned cnt = 0;
    if (lds) {
        for (unsigned i = lane; i < n; i += 64) {
            unsigned my = keys[w][i];
            bool rep = true;
            for (unsigned j = 0; j < i; j++)
                if (keys[w][j] == my) { rep = false; break; }
            cnt += rep ? 1u : 0u;
        }
    } else {
        for (unsigned i = lane; i < n; i += 64) {
            unsigned my = bPair[s + i].x;
            bool rep = true;
            for (unsigned j = 0; j < i; j++)
                if (bPair[s + j].x == my) { rep = false; break; }
            cnt += rep ? 1u : 0u;
        }
    }
#pragma unroll
    for (int o = 32; o > 0; o >>= 1) cnt += __shfl_down(cnt, o);
    if (lane == 0) dcnt[b] = cnt;
}

__device__ __forceinline__ void decode_key(unsigned sk, int* iua, int* iub) {
    int key = (int)(sk ^ 0x80000000u);
    long long kk = (long long)key;
    long long q = kk / 300000LL;
    long long r = kk - q * 300000LL;
    if (r < 0) { q -= 1; r += 300000LL; }
    int ua = (int)q;
    if (ua < 0) ua += NVV;
    *iua = ua;
    *iub = (int)r;
}

__device__ __forceinline__ void write_vert(unsigned sk, unsigned g,
                                           const float* __restrict__ pos,
                                           const float* __restrict__ sdf,
                                           float* __restrict__ out_verts,
                                           float* __restrict__ out_cross) {
    int ua, ub;
    decode_key(sk, &ua, &ub);
    float s0 = sdf[ua], s1 = sdf[ub];
    bool cr = (s0 > 0.0f) != (s1 > 0.0f);
    out_cross[g] = cr ? 1.0f : 0.0f;
    if (cr) {
        float denom = s0 - s1;
        float wa = -s1 / denom, wb = s0 / denom;
        out_verts[g * 3 + 0] = wa * pos[ua * 3 + 0] + wb * pos[ub * 3 + 0];
        out_verts[g * 3 + 1] = wa * pos[ua * 3 + 1] + wb * pos[ub * 3 + 1];
        out_verts[g * 3 + 2] = wa * pos[ua * 3 + 2] + wb * pos[ub * 3 + 2];
    }
}

// K3: wave-per-bucket ranks — packed register bitonic fast path
__global__ void k3_rank(const float* __restrict__ pos, const float* __restrict__ sdf,
                        const unsigned* __restrict__ off1, const uint2* __restrict__ bPair,
                        const unsigned* __restrict__ base2, const unsigned* __restrict__ flags,
                        unsigned* __restrict__ idx_map,
                        float* __restrict__ out_verts, float* __restrict__ out_cross) {
    __shared__ unsigned keys[4][BCAP];
    __shared__ unsigned origs[4][BCAP];
    __shared__ unsigned char repf[4][BCAP];
    int w = threadIdx.x >> 6, lane = threadIdx.x & 63;
    unsigned b = blockIdx.x * 4u + (unsigned)w;
    unsigned s = off1[b], e = off1[b + 1];
    unsigned n = e - s;
    bool fast = (n <= 64u);
    bool lds = !fast && (n <= BCAP);
    bool needZ = (flags[0] != 0u) && (flags[1] == 0u);
    unsigned bb = base2[b];
    if (lds) for (unsigned i = lane; i < n; i += 64) {
        uint2 t = bPair[s + i];
        keys[w][i] = t.x;
        origs[w][i] = t.y;
    }
    __syncthreads();
    if (lds) for (unsigned i = lane; i < n; i += 64) {
        unsigned my = keys[w][i];
        unsigned char r = 1;
        for (unsigned j = 0; j < i; j++)
            if (keys[w][j] == my) { r = 0; break; }
        repf[w][i] = r;
    }
    __syncthreads();
    if (fast) {
        unsigned long long v = 0xFFFFFFFFFFFFFFFFull;
        if (lane < (int)n) {
            uint2 t = bPair[s + lane];
            v = ((unsigned long long)t.x << 32) | t.y;
        }
        v = bitonic64p(v, lane);
        unsigned key = (unsigned)(v >> 32);
        unsigned org = (unsigned)v;
        bool valid = (v != 0xFFFFFFFFFFFFFFFFull);
        unsigned prev = __shfl_up(key, 1, 64);
        bool rep = valid && (lane == 0 || key != prev);
        unsigned long long m = __ballot(rep);
        unsigned prefix = (unsigned)__popcll(m & ((1ull << lane) - 1ull));
        // distinct rank: duplicates must NOT count their own run's rep
        unsigned rank = prefix - ((valid && !rep) ? 1u : 0u);
        unsigned g = bb + rank + ((needZ && key > 0x80000000u) ? 1u : 0u);
        if (valid) idx_map[org] = g;
        if (rep) write_vert(key, g, pos, sdf, out_verts, out_cross);
        return;
    }
    if (lds) {
        for (unsigned i = lane; i < n; i += 64) {
            unsigned my = keys[w][i];
            unsigned rank = 0;
            for (unsigned j = 0; j < n; j++)
                rank += (repf[w][j] && keys[w][j] < my) ? 1u : 0u;
            unsigned g = bb + rank + ((needZ && my > 0x80000000u) ? 1u : 0u);
            idx_map[origs[w][i]] = g;
            if (repf[w][i]) write_vert(my, g, pos, sdf, out_verts, out_cross);
        }
    } else {
        for (unsigned i = lane; i < n; i += 64) {
            unsigned my = bPair[s + i].x;
            bool isrep = true;
            for (unsigned j = 0; j < i; j++)
                if (bPair[s + j].x == my) { isrep = false; break; }
            unsigned rank = 0;
            for (unsigned j = 0; j < n; j++) {
                unsigned kj = bPair[s + j].x;
                if (kj < my) {
                    bool jr = true;
                    for (unsigned k = 0; k < j; k++)
                        if (bPair[s + k].x == kj) { jr = false; break; }
                    rank += jr ? 1u : 0u;
                }
            }
            unsigned g = bb + rank + ((needZ && my > 0x80000000u) ? 1u : 0u);
            idx_map[bPair[s + i].y] = g;
            if (isrep) write_vert(my, g, pos, sdf, out_verts, out_cross);
        }
    }
}

// K5: faces — coalesced gather from idx_map (u32, same buffer), overwrite as float
__global__ void k5_faces(const int* __restrict__ tets, const float* __restrict__ sdf,
                         void* faces_buf) {
    int f = blockIdx.x * 256 + threadIdx.x;
    if (f >= NFF) return;
    const int4 tv = ((const int4*)tets)[f];
    int v0 = tv.x, v1 = tv.y, v2 = tv.z, v3 = tv.w;
    int ti = tidx(sdf, v0, v1, v2, v3);
    unsigned row = TROW[ti];
    bool has1 = (row & 7u) != 7u;
    bool has2 = ((row >> 9) & 7u) != 7u;
    float* of = (float*)faces_buf + (size_t)f * 6;
    if (!has1) {
        of[0] = -1.0f; of[1] = -1.0f; of[2] = -1.0f;
        of[3] = -1.0f; of[4] = -1.0f; of[5] = -1.0f;
        return;
    }
    const unsigned* im = (const unsigned*)faces_buf + (size_t)f * 6;
    float g0 = (float)im[0], g1 = (float)im[1], g2 = (float)im[2];
    float g3 = (float)im[3], g4 = (float)im[4], g5 = (float)im[5];
    unsigned l0 = row & 7u,         l1 = (row >> 3) & 7u,  l2 = (row >> 6) & 7u;
    unsigned l3 = (row >> 9) & 7u,  l4 = (row >> 12) & 7u, l5 = (row >> 15) & 7u;
#define SEL(L) ((L) == 0u ? g0 : (L) == 1u ? g1 : (L) == 2u ? g2 : \
                (L) == 3u ? g3 : (L) == 4u ? g4 : g5)
    float o0 = SEL(l0), o1 = SEL(l1), o2 = SEL(l2);
    float o3 = has2 ? SEL(l3) : -1.0f;
    float o4 = has2 ? SEL(l4) : -1.0f;
    float o5 = has2 ? SEL(l5) : -1.0f;
#undef SEL
    of[0] = o0; of[1] = o1; of[2] = o2;
    of[3] = o3; of[4] = o4; of[5] = o5;
}

// K6: uv atlas — runs LAST over the uvs region
__global__ void k6_uvs(float* __restrict__ out_uvs) {
    int c = blockIdx.x * 256 + threadIdx.x;
    if (c >= NGRID * NGRID) return;
    int i = c / NGRID, j = c - i * NGRID;
    const float inv = 1.0f / (float)NGRID;
    const float pad = 0.9f / (float)NGRID;
    float x = (float)j * inv;
    float y = (float)i * inv;
    float4* o = (float4*)(out_uvs + (size_t)c * 8);
    o[0] = make_float4(x, y, x + pad, y);
    o[1] = make_float4(x + pad, y + pad, x, y + pad);
}

// K7: uv_idx — runs LAST over the uv_idx region
__global__ void k7_uvidx(float* __restrict__ out_uvidx) {
    int f = blockIdx.x * 256 + threadIdx.x;
    if (f >= NFF) return;
    float base = (float)(4 * f);
    float2* uvi = (float2*)(out_uvidx + (size_t)f * 6);
    uvi[0] = make_float2(base, base + 1.0f);
    uvi[1] = make_float2(base + 2.0f, base);
    uvi[2] = make_float2(base + 2.0f, base + 3.0f);
}

extern "C" void kernel_launch(void* const* d_in, const int* in_sizes, int n_in,
                              void* d_out, int out_size, void* d_ws, size_t ws_size,
                              hipStream_t stream) {
    const float* pos = (const float*)d_in[0];
    const float* sdf = (const float*)d_in[1];
    const int* tets = (const int*)d_in[2];
    float* out = (float*)d_out;
    unsigned* u = (unsigned*)d_out;

    uint2*    bPair   = (uint2*)(u + S_PAIR);
    unsigned* gHist   = u + S_GH;
    unsigned* gScan   = u + S_GS;
    unsigned* dcnt    = u + S_DCNT;
    unsigned* off1    = u + S_OFF1;
    unsigned* base2   = u + S_BASE2;
    unsigned* bsums   = u + S_BSUMS;
    unsigned* ssums   = u + S_SSUMS;
    unsigned* flags   = u + S_FLG;
    unsigned* idx_map = u + OFF_FACES;
    uint2*    staging = (uint2*)(u + OFF_VERTS);   // verts region until kC done

    hipMemsetAsync(flags, 0, 8 * 4, stream);
    hipMemsetAsync(out + OFF_CROSS, 0, (size_t)9000000 * 4, stream);

    dim3 blk(256);
    int gF = (NFF + 255) / 256;
    int gB = NB / 4;

    kA_hist<<<NBLK1, blk, 0, stream>>>(tets, sdf, gHist, flags,
                                       out + OFF_NTRI, out + OFF_MASK);

    scan_block<<<NHIST / 1024, 1024, 0, stream>>>(gHist, gScan, bsums, NHIST);
    scan_block<<<1, 1024, 0, stream>>>(bsums, ssums, nullptr, NHIST / 1024);
    scan_add<<<NHIST / 1024, 1024, 0, stream>>>(gScan, ssums, gHist, off1 + NB, NHIST);

    kB_scatter<<<NBLK1, blk, 0, stream>>>(tets, sdf, gScan, staging);
    kC_fine<<<NC, blk, 0, stream>>>(gScan, off1 + NB, staging, bPair, off1);

    hipMemsetAsync(out + OFF_VERTS, 0, (size_t)27000000 * 4, stream);

    k2_count<<<gB, blk, 0, stream>>>(off1, bPair, dcnt);

    scan_block<<<NB / 1024, 1024, 0, stream>>>(dcnt, base2, bsums, NB);
    scan_block<<<1, 1024, 0, stream>>>(bsums, ssums, nullptr, NB / 1024);
    scan_add<<<NB / 1024, 1024, 0, stream>>>(base2, ssums, dcnt, base2 + NB, NB);

    k3_rank<<<gB, blk, 0, stream>>>(pos, sdf, off1, bPair, base2, flags,
                                    idx_map, out + OFF_VERTS, out + OFF_CROSS);
    k5_faces<<<gF, blk, 0, stream>>>(tets, sdf, (void*)(out + OFF_FACES));

    int gC = (NGRID * NGRID + 255) / 256;
    k6_uvs<<<gC, blk, 0, stream>>>(out + OFF_UVS);
    k7_uvidx<<<gF, blk, 0, stream>>>(out + OFF_UVIDX);
}